// Round 7
// baseline (547.715 us; speedup 1.0000x reference)
//
#include <hip/hip_runtime.h>
#include <hip/hip_bf16.h>
#include <math.h>

#define DIMK 1024
#define NH 16
#define HD 64
#define BB 4
#define SS 8192
#define EPAD 136
#define NTK 48  // K' = 3072 / BK=64 K-steps

typedef __attribute__((ext_vector_type(8))) short bf16x8;
typedef __attribute__((ext_vector_type(8))) unsigned short ushort8;
typedef __attribute__((ext_vector_type(4))) unsigned short us4;
typedef __attribute__((ext_vector_type(4))) float f32x4;

#define MFMA16(a, b, c) __builtin_amdgcn_mfma_f32_16x16x32_bf16((a), (b), (c), 0, 0, 0)

__device__ __forceinline__ unsigned short f32_to_bf16_rne(float f) {
  unsigned int u = __float_as_uint(f);
  u = (u + 0x7fffu + ((u >> 16) & 1u)) >> 16;
  return (unsigned short)u;
}
__device__ __forceinline__ float bf16_bits_to_f32(unsigned short b) {
  return __uint_as_float(((unsigned int)b) << 16);
}
__device__ __forceinline__ void gload16(const void* g, void* l) {
  __builtin_amdgcn_global_load_lds((const __attribute__((address_space(1))) void*)g,
                                   (__attribute__((address_space(3))) void*)l, 16, 0, 0);
}

// ---------------- fill d_out with bo broadcast ----------------
__global__ __launch_bounds__(256) void fill_out_kernel(const float4* __restrict__ bo4,
                                                       float4* __restrict__ out, int total4) {
  for (int i = blockIdx.x * 256 + threadIdx.x; i < total4; i += gridDim.x * 256)
    out[i] = bo4[i & 255];
}

// ---------------- W [k][n] fp32 -> tiled+swizzled bf16 hi/lo panels (all 4 weights) ----------------
// B layout: panel p = pn*64 + kt (hi) / pn*64+32+kt (lo); panel = [128 n-rows][32 k] 8KB,
// chunk swizzle q' = q ^ ((r>>1)&3).
__global__ __launch_bounds__(256) void prep_w4(
    const float* __restrict__ Wq, const float* __restrict__ Wk,
    const float* __restrict__ Wv, const float* __restrict__ Wo,
    unsigned short* __restrict__ Bq, unsigned short* __restrict__ Bkv,
    unsigned short* __restrict__ Bo) {
  const float* W;
  unsigned short* Bpan;
  int pnoff;
  switch (blockIdx.z) {
    case 0: W = Wq; Bpan = Bq; pnoff = 0; break;
    case 1: W = Wk; Bpan = Bkv; pnoff = 0; break;
    case 2: W = Wv; Bpan = Bkv; pnoff = 8; break;
    default: W = Wo; Bpan = Bo; pnoff = 0; break;
  }
  __shared__ float st[64][65];
  const int bk = blockIdx.x * 64, bn = blockIdx.y * 64;
  const int t = threadIdx.x;
  const int lr = t >> 4, lc = (t & 15) * 4;
#pragma unroll
  for (int i = 0; i < 4; i++) {
    int k = lr + i * 16;
    float4 v = *(const float4*)(W + (size_t)(bk + k) * DIMK + bn + lc);
    st[k][lc] = v.x; st[k][lc + 1] = v.y; st[k][lc + 2] = v.z; st[k][lc + 3] = v.w;
  }
  __syncthreads();
  const int ktile = (bk + lc) >> 5, c = lc & 31;
#pragma unroll
  for (int i = 0; i < 4; i++) {
    const int nl = lr + i * 16;
    const int n = bn + nl;
    const int r = n & 127, pn = (n >> 7) + pnoff;
    const int q = (c >> 3) ^ ((r >> 1) & 3);
    const size_t byteoff = (size_t)r * 64 + q * 16 + (c & 7) * 2;
    us4 hv, lv;
#pragma unroll
    for (int j = 0; j < 4; j++) {
      float v = st[lc + j][nl];
      unsigned short hb = f32_to_bf16_rne(v);
      hv[j] = hb;
      lv[j] = f32_to_bf16_rne(v - bf16_bits_to_f32(hb));
    }
    char* base = (char*)Bpan;
    *(us4*)(base + (((size_t)pn * 64 + ktile) << 13) + byteoff) = hv;
    *(us4*)(base + (((size_t)pn * 64 + 32 + ktile) << 13) + byteoff) = lv;
  }
}

// ---------------- split W1 [128][64] fp32 -> W1T hi/lo [64][128] bf16 ----------------
__global__ __launch_bounds__(256) void prep_w1(const float* __restrict__ W1,
                                               unsigned short* __restrict__ W1Th,
                                               unsigned short* __restrict__ W1Tl) {
  for (int idx = threadIdx.x; idx < 128 * 64; idx += 256) {
    int k = idx >> 6, n = idx & 63;
    float v = W1[idx];
    unsigned short hb = f32_to_bf16_rne(v);
    W1Th[n * 128 + k] = hb;
    W1Tl[n * 128 + k] = f32_to_bf16_rne(v - bf16_bits_to_f32(hb));
  }
}

// ---------------- gather rows of X -> tiled+swizzled bf16 hi/lo A panels ----------------
__global__ __launch_bounds__(256) void prep_a(const float* __restrict__ X,
                                              const int* __restrict__ gidx,
                                              unsigned short* __restrict__ Apan, int M, int E) {
  const int row = blockIdx.x;  // < Mpad
  const int r = row & 255, mt = row >> 8;
  const int c0 = threadIdx.x * 4;
  const int kt = c0 >> 5, c = c0 & 31;
  const int q = (c >> 3) ^ ((r >> 1) & 3);
  const size_t byteoff = (size_t)r * 64 + q * 16 + (c & 7) * 2;
  char* base = (char*)Apan;
  us4 hv = (us4){0, 0, 0, 0}, lv = (us4){0, 0, 0, 0};
  if (row < M) {
    const float* sr;
    if (gidx) {
      int b = row / E, e = row - b * E;
      sr = X + ((size_t)b * SS + gidx[e]) * DIMK;
    } else {
      sr = X + (size_t)row * DIMK;
    }
    float4 v = *(const float4*)(sr + c0);
    float vv[4] = {v.x, v.y, v.z, v.w};
#pragma unroll
    for (int i = 0; i < 4; i++) {
      unsigned short hb = f32_to_bf16_rne(vv[i]);
      hv[i] = hb;
      lv[i] = f32_to_bf16_rne(vv[i] - bf16_bits_to_f32(hb));
    }
  }
  *(us4*)(base + (((size_t)(mt * 64 + kt)) << 14) + byteoff) = hv;
  *(us4*)(base + (((size_t)(mt * 64 + 32 + kt)) << 14) + byteoff) = lv;
}

// ---------------- first-occurrence map, single block, LDS table ----------------
__global__ __launch_bounds__(1024) void first_occ(const int* __restrict__ src,
                                                  int* __restrict__ fidx,
                                                  int* __restrict__ mark, int E) {
  __shared__ int tbl[SS];
  for (int i = threadIdx.x; i < SS; i += 1024) tbl[i] = 0x7fffffff;
  __syncthreads();
  for (int e = threadIdx.x; e < E; e += 1024) atomicMin(&tbl[src[e]], e);
  __syncthreads();
  for (int e = threadIdx.x; e < E; e += 1024) mark[e] = 0;
  __syncthreads();
  for (int e = threadIdx.x; e < E; e += 1024) {
    int f = tbl[src[e]];
    fidx[e] = f;
    if (f != e) mark[f] = 1;
  }
}

// ---------------- 8-phase deep-pipelined K-concat bf16 GEMM (m201-style) ----------------
// 256x256 tile, BK=64 (2 x kt32 halves), 8 waves (2Mx4N), 4x16KB LDS slots per operand.
// Per K-step s: 4 phases, each {ds_read, issue 1 half-tile stage, bar, lgkmcnt0, prio,
// 16 MFMA, prio, bar}; vmcnt(6) once per K-step. Stage targets: issue-after-death order.
// MODE 0: out[m*ldc+n] = acc + bias_sel(n). MODE 1: scatter to out[(b*SS+srci[e])*ldc+n]
// iff fidx[e]==e.
template <int MODE>
__global__ __launch_bounds__(512, 2) void gemm256(
    const unsigned short* __restrict__ Apan, const unsigned short* __restrict__ Bpan,
    const float* __restrict__ bias, const float* __restrict__ bias2,
    float* __restrict__ out, int ldc, int nty,
    const int* __restrict__ fidx, const int* __restrict__ srci, int M, int E) {
  __shared__ unsigned short ldsA[4][8192];
  __shared__ unsigned short ldsB[4][8192];

  const int tid = threadIdx.x, lane = tid & 63, wv = tid >> 6;
  const int wr = wv >> 2, wc = wv & 3;

  const int w = (blockIdx.x & 7) * ((int)gridDim.x >> 3) + ((int)blockIdx.x >> 3);
  const int mt = w / nty, nt_ = w - mt * nty;
  const int m0 = mt * 256, n0 = nt_ * 256;

  const int rr = lane & 15, lq = lane >> 4;
  const int swz = (rr >> 1) & 3;
  const int aoff = (wr * 128 + rr) * 32 + ((lq ^ swz) << 3);  // + mf*512
  const int boff = (wc * 64 + rr) * 32 + ((lq ^ swz) << 3);   // + nf*512

  const char* Apb = (const char*)Apan + ((size_t)(mt * 64) << 14);
  const char* Bpb = (const char*)Bpan;
  const int stoff = wv * 1024 + lane * 16;

  f32x4 acc[8][4];
#pragma unroll
  for (int i = 0; i < 8; i++)
#pragma unroll
    for (int j = 0; j < 4; j++) acc[i][j] = (f32x4){0.f, 0.f, 0.f, 0.f};

  auto stA = [&](int kt) {
    const int apk = kt < 64 ? kt : kt - 64;  // A' = [Ah | Al | Ah]
    const char* s = Apb + ((size_t)apk << 14) + stoff;
    gload16(s, &ldsA[kt & 3][wv * 512]);
    gload16(s + 8192, &ldsA[kt & 3][wv * 512 + 4096]);
  };
  auto stB = [&](int kt) {
    const int bpk = kt < 32 ? kt : kt - 32;  // B' = [Bh ; Bh ; Bl]
    const char* s0 = Bpb + (((size_t)(2 * nt_) * 64 + bpk) << 13) + stoff;
    const char* s1 = Bpb + (((size_t)(2 * nt_ + 1) * 64 + bpk) << 13) + stoff;
    gload16(s0, &ldsB[kt & 3][wv * 512]);
    gload16(s1, &ldsB[kt & 3][wv * 512 + 4096]);
  };

  // prologue: K0 fully + K1 minus A-kh1 (loop's P1(0) issues it)
  stA(0); stB(0); stA(1); stB(1); stB(2); stA(2); stB(3);
  asm volatile("s_waitcnt vmcnt(6)" ::: "memory");  // K0's 4 halves landed
  __builtin_amdgcn_sched_barrier(0);
  __builtin_amdgcn_s_barrier();

  for (int s = 0; s < NTK; ++s) {
    const unsigned short* A0 = ldsA[(2 * s) & 3];
    const unsigned short* A1 = ldsA[(2 * s + 1) & 3];
    const unsigned short* B0 = ldsB[(2 * s) & 3];
    const unsigned short* B1 = ldsB[(2 * s + 1) & 3];

    bf16x8 fb[4], fa[4];
    // ---- P1: kh0, mf0-3 x nf0-3 ----
#pragma unroll
    for (int nf = 0; nf < 4; ++nf) fb[nf] = *(const bf16x8*)(B0 + boff + nf * 512);
#pragma unroll
    for (int mf = 0; mf < 4; ++mf) fa[mf] = *(const bf16x8*)(A0 + aoff + mf * 512);
    if (s < NTK - 1) stA(2 * s + 3);  // A-kh1(s+1); its target died at P4(s-1)
    __builtin_amdgcn_s_barrier();
    asm volatile("s_waitcnt lgkmcnt(0)" ::: "memory");
    __builtin_amdgcn_sched_barrier(0);
    __builtin_amdgcn_s_setprio(1);
#pragma unroll
    for (int mf = 0; mf < 4; ++mf)
#pragma unroll
      for (int nf = 0; nf < 4; ++nf) acc[mf][nf] = MFMA16(fa[mf], fb[nf], acc[mf][nf]);
    __builtin_amdgcn_s_setprio(0);
    __builtin_amdgcn_s_barrier();
    __builtin_amdgcn_sched_barrier(0);

    // ---- P2: kh0, mf4-7 x nf0-3 (fb reused) ----
#pragma unroll
    for (int mf = 0; mf < 4; ++mf) fa[mf] = *(const bf16x8*)(A0 + aoff + (mf + 4) * 512);
    if (s < NTK - 2) stB(2 * s + 4);  // B-kh0(s+2); target died at P1(s)
    __builtin_amdgcn_s_barrier();
    asm volatile("s_waitcnt lgkmcnt(0)" ::: "memory");
    __builtin_amdgcn_sched_barrier(0);
    __builtin_amdgcn_s_setprio(1);
#pragma unroll
    for (int mf = 0; mf < 4; ++mf)
#pragma unroll
      for (int nf = 0; nf < 4; ++nf) acc[mf + 4][nf] = MFMA16(fa[mf], fb[nf], acc[mf + 4][nf]);
    __builtin_amdgcn_s_setprio(0);
    __builtin_amdgcn_s_barrier();
    __builtin_amdgcn_sched_barrier(0);

    // ---- P3: kh1, mf0-3 x nf0-3 ----
#pragma unroll
    for (int nf = 0; nf < 4; ++nf) fb[nf] = *(const bf16x8*)(B1 + boff + nf * 512);
#pragma unroll
    for (int mf = 0; mf < 4; ++mf) fa[mf] = *(const bf16x8*)(A1 + aoff + mf * 512);
    if (s < NTK - 2) stA(2 * s + 4);  // A-kh0(s+2); target died at P2(s)
    __builtin_amdgcn_s_barrier();
    asm volatile("s_waitcnt lgkmcnt(0)" ::: "memory");
    __builtin_amdgcn_sched_barrier(0);
    __builtin_amdgcn_s_setprio(1);
#pragma unroll
    for (int mf = 0; mf < 4; ++mf)
#pragma unroll
      for (int nf = 0; nf < 4; ++nf) acc[mf][nf] = MFMA16(fa[mf], fb[nf], acc[mf][nf]);
    __builtin_amdgcn_s_setprio(0);
    __builtin_amdgcn_s_barrier();
    __builtin_amdgcn_sched_barrier(0);

    // ---- P4: kh1, mf4-7 x nf0-3 (fb reused) ----
#pragma unroll
    for (int mf = 0; mf < 4; ++mf) fa[mf] = *(const bf16x8*)(A1 + aoff + (mf + 4) * 512);
    if (s < NTK - 2) stB(2 * s + 5);  // B-kh1(s+2); target died at P3(s)
    __builtin_amdgcn_s_barrier();
    asm volatile("s_waitcnt lgkmcnt(0)" ::: "memory");
    __builtin_amdgcn_sched_barrier(0);
    __builtin_amdgcn_s_setprio(1);
#pragma unroll
    for (int mf = 0; mf < 4; ++mf)
#pragma unroll
      for (int nf = 0; nf < 4; ++nf) acc[mf + 4][nf] = MFMA16(fa[mf], fb[nf], acc[mf + 4][nf]);
    __builtin_amdgcn_s_setprio(0);

    // K-step boundary: counted vmcnt (never drain in steady state)
    if (s < NTK - 2) {
      asm volatile("s_waitcnt vmcnt(6)" ::: "memory");  // next K-step fully landed
    } else if (s == NTK - 2) {
      asm volatile("s_waitcnt vmcnt(0)" ::: "memory");  // drain before last K-step
    }
    __builtin_amdgcn_sched_barrier(0);
    if (s < NTK - 1) __builtin_amdgcn_s_barrier();
  }

  // epilogue: C layout col=lane&15, row=(lane>>4)*4+r
  const int cq = lane >> 4, cr = lane & 15;
#pragma unroll
  for (int nf = 0; nf < 4; ++nf) {
    const int col = n0 + wc * 64 + nf * 16 + cr;
    const float bv = (MODE == 0 && bias2 != nullptr && col >= DIMK) ? bias2[col - DIMK]
                                                                    : bias[col & (DIMK - 1)];
#pragma unroll
    for (int mf = 0; mf < 8; ++mf) {
#pragma unroll
      for (int r = 0; r < 4; ++r) {
        const int mrow = m0 + wr * 128 + mf * 16 + cq * 4 + r;
        if (mrow >= M) continue;
        if (MODE == 0) {
          out[(size_t)mrow * ldc + col] = acc[mf][nf][r] + bv;
        } else {
          int b = mrow / E, e = mrow - b * E;
          if (fidx[e] == e) {
            int orow = b * SS + srci[e];
            out[(size_t)orow * ldc + col] = acc[mf][nf][r] + bv;
          }
        }
      }
    }
  }
}

// ---------------- edge MLP scores + softmax + edge_weight, fused ----------------
// One block per (b,h); scores live in LDS; writes final attn.
__global__ __launch_bounds__(256) void edge_sm(
    const float* __restrict__ qs, const float* __restrict__ kd, int ldk,
    const unsigned short* __restrict__ W1Th, const unsigned short* __restrict__ W1Tl,
    const float* __restrict__ b1, const float* __restrict__ W2,
    const float* __restrict__ b2, const float* __restrict__ ew,
    float* __restrict__ attn, int E) {
  __shared__ unsigned short W1h[64][EPAD], W1l[64][EPAD];
  __shared__ unsigned short EFh[4][16][EPAD], EFl[4][16][EPAD];
  __shared__ float scl[2048];
  __shared__ float red[4];
  const int tid = threadIdx.x, lane = tid & 63, w = tid >> 6;
  const int b = blockIdx.x >> 4, h = blockIdx.x & 15;

  for (int idx = tid; idx < 64 * 16; idx += 256) {
    int n = idx >> 4, g = (idx & 15) * 8;
    *(ushort8*)&W1h[n][g] = *(const ushort8*)(W1Th + n * 128 + g);
    *(ushort8*)&W1l[n][g] = *(const ushort8*)(W1Tl + n * 128 + g);
  }
  __syncthreads();

  const int etiles = (E + 15) / 16;
  const int r = lane >> 2, c0 = (lane & 3) * 16;
  const int kk = (lane >> 4) * 8, rrl = lane & 15;
  const int col_l = lane & 15, rq = lane >> 4;
  float w2v[4], b1v[4];
#pragma unroll
  for (int nf = 0; nf < 4; nf++) {
    w2v[nf] = W2[nf * 16 + col_l];
    b1v[nf] = b1[nf * 16 + col_l];
  }
  const float b2v = b2[0];

  for (int t = w; t < etiles; t += 4) {
    const int e0 = t * 16;
    {
      const int er = (e0 + r < E) ? e0 + r : E - 1;
      const float* qrow = qs + ((size_t)(b * E + er)) * DIMK + h * HD + c0;
      const float* krow = kd + ((size_t)(b * E + er)) * (size_t)ldk + h * HD + c0;
      float qv[16], kvv[16];
#pragma unroll
      for (int i = 0; i < 4; i++) {
        *(float4*)&qv[i * 4] = *(const float4*)(qrow + i * 4);
        *(float4*)&kvv[i * 4] = *(const float4*)(krow + i * 4);
      }
      ushort8 qh[2], ql[2], kh[2], kl[2];
#pragma unroll
      for (int g = 0; g < 2; g++)
#pragma unroll
        for (int i = 0; i < 8; i++) {
          float v = qv[g * 8 + i];
          unsigned short hb = f32_to_bf16_rne(v);
          qh[g][i] = hb;
          ql[g][i] = f32_to_bf16_rne(v - bf16_bits_to_f32(hb));
          float v2 = kvv[g * 8 + i];
          unsigned short hb2 = f32_to_bf16_rne(v2);
          kh[g][i] = hb2;
          kl[g][i] = f32_to_bf16_rne(v2 - bf16_bits_to_f32(hb2));
        }
      *(ushort8*)&EFh[w][r][c0] = qh[0];
      *(ushort8*)&EFh[w][r][c0 + 8] = qh[1];
      *(ushort8*)&EFl[w][r][c0] = ql[0];
      *(ushort8*)&EFl[w][r][c0 + 8] = ql[1];
      *(ushort8*)&EFh[w][r][64 + c0] = kh[0];
      *(ushort8*)&EFh[w][r][64 + c0 + 8] = kh[1];
      *(ushort8*)&EFl[w][r][64 + c0] = kl[0];
      *(ushort8*)&EFl[w][r][64 + c0 + 8] = kl[1];
    }
    asm volatile("s_waitcnt lgkmcnt(0)" ::: "memory");
    __builtin_amdgcn_sched_barrier(0);

    f32x4 acc[4];
#pragma unroll
    for (int i = 0; i < 4; i++) acc[i] = (f32x4){0.f, 0.f, 0.f, 0.f};
#pragma unroll
    for (int ks = 0; ks < 4; ks++) {
      bf16x8 ah = *(bf16x8*)&EFh[w][rrl][ks * 32 + kk];
      bf16x8 al = *(bf16x8*)&EFl[w][rrl][ks * 32 + kk];
#pragma unroll
      for (int nf = 0; nf < 4; nf++) {
        bf16x8 bh_ = *(bf16x8*)&W1h[nf * 16 + rrl][ks * 32 + kk];
        bf16x8 bl_ = *(bf16x8*)&W1l[nf * 16 + rrl][ks * 32 + kk];
        acc[nf] = MFMA16(ah, bh_, acc[nf]);
        acc[nf] = MFMA16(ah, bl_, acc[nf]);
        acc[nf] = MFMA16(al, bh_, acc[nf]);
      }
    }

    float p[4];
#pragma unroll
    for (int rr2 = 0; rr2 < 4; rr2++) {
      float sdot = 0.f;
#pragma unroll
      for (int nf = 0; nf < 4; nf++) {
        float hv = acc[nf][rr2] + b1v[nf];
        hv = 0.5f * hv * (1.f + erff(hv * 0.70710678118654752f));
        sdot = fmaf(hv, w2v[nf], sdot);
      }
      p[rr2] = sdot;
    }
#pragma unroll
    for (int off = 1; off < 16; off <<= 1)
#pragma unroll
      for (int rr2 = 0; rr2 < 4; rr2++) p[rr2] += __shfl_xor(p[rr2], off, 64);

    if (col_l == 0) {
#pragma unroll
      for (int rr2 = 0; rr2 < 4; rr2++) {
        int e = e0 + rq * 4 + rr2;
        if (e < E) scl[e] = (p[rr2] + b2v) * 0.125f;
      }
    }
  }
  __syncthreads();

  // block softmax over scl[0..E), then *= ew[h]
  float vals[8];
  float mx = -1e30f;
#pragma unroll
  for (int i = 0; i < 8; i++) {
    int j = tid + i * 256;
    vals[i] = (j < E) ? scl[j] : -1e30f;
    mx = fmaxf(mx, vals[i]);
  }
#pragma unroll
  for (int off = 32; off; off >>= 1) mx = fmaxf(mx, __shfl_xor(mx, off, 64));
  if (lane == 0) red[w] = mx;
  __syncthreads();
  mx = fmaxf(fmaxf(red[0], red[1]), fmaxf(red[2], red[3]));
  __syncthreads();

  float sum = 0.f;
#pragma unroll
  for (int i = 0; i < 8; i++) {
    vals[i] = __expf(vals[i] - mx);
    if (tid + i * 256 < E) sum += vals[i];
  }
#pragma unroll
  for (int off = 32; off; off >>= 1) sum += __shfl_xor(sum, off, 64);
  if (lane == 0) red[w] = sum;
  __syncthreads();
  sum = red[0] + red[1] + red[2] + red[3];

  const float scaleout = ew[h] / sum;
  float* arow = attn + (size_t)(b * NH + h) * E;
#pragma unroll
  for (int i = 0; i < 8; i++) {
    int j = tid + i * 256;
    if (j < E) arow[j] = vals[i] * scaleout;
  }
}

// ---------------- weight rows (attn * v) + write fp32 wrow + split A panels ----------------
__global__ __launch_bounds__(256) void weight_split(
    const float* __restrict__ vd, int ldv, const float* __restrict__ attn,
    float* __restrict__ wrow, unsigned short* __restrict__ Apan, int M, int E) {
  const int row = blockIdx.x;  // < Mpad
  const int r = row & 255, mt = row >> 8;
  const int c0 = threadIdx.x * 4;
  const int kt = c0 >> 5, c = c0 & 31;
  const int q = (c >> 3) ^ ((r >> 1) & 3);
  const size_t byteoff = (size_t)r * 64 + q * 16 + (c & 7) * 2;
  char* base = (char*)Apan;
  us4 hv = (us4){0, 0, 0, 0}, lv = (us4){0, 0, 0, 0};
  if (row < M) {
    const int b = row / E, e = row - b * E;
    const float a = attn[(size_t)(b * NH + (c0 >> 6)) * E + e];
    float4 v = *(const float4*)(vd + (size_t)row * ldv + c0);
    v.x *= a; v.y *= a; v.z *= a; v.w *= a;
    *(float4*)(wrow + (size_t)row * DIMK + c0) = v;
    float vv[4] = {v.x, v.y, v.z, v.w};
#pragma unroll
    for (int i = 0; i < 4; i++) {
      unsigned short hb = f32_to_bf16_rne(vv[i]);
      hv[i] = hb;
      lv[i] = f32_to_bf16_rne(vv[i] - bf16_bits_to_f32(hb));
    }
  }
  *(us4*)(base + (((size_t)(mt * 64 + kt)) << 14) + byteoff) = hv;
  *(us4*)(base + (((size_t)(mt * 64 + 32 + kt)) << 14) + byteoff) = lv;
}

// ---------------- fold duplicate-src edges into primary rows (fp32 wrow) ----------------
__global__ __launch_bounds__(256) void dup_add(const int* __restrict__ f,
                                               float* __restrict__ wrow, int E) {
  const int e = blockIdx.x;
  const int fe = f[e];
  if (fe == e) return;
  const int d = threadIdx.x * 4;
#pragma unroll
  for (int b = 0; b < BB; b++) {
    const float4 v = *(const float4*)(wrow + (size_t)(b * E + e) * DIMK + d);
    float* dst = wrow + (size_t)(b * E + fe) * DIMK + d;
    atomicAdd(dst + 0, v.x);
    atomicAdd(dst + 1, v.y);
    atomicAdd(dst + 2, v.z);
    atomicAdd(dst + 3, v.w);
  }
}

// ---------------- re-split panels for primary rows that received duplicates ----------------
__global__ __launch_bounds__(256) void dup_fix(const int* __restrict__ fidx,
                                               const int* __restrict__ mark,
                                               const float* __restrict__ wrow,
                                               unsigned short* __restrict__ Apan, int E) {
  const int e = blockIdx.x;
  if (fidx[e] != e || !mark[e]) return;
  const int c0 = threadIdx.x * 4;
  const int kt = c0 >> 5, c = c0 & 31;
  char* base = (char*)Apan;
  for (int b = 0; b < BB; b++) {
    const int row = b * E + e;
    const int r = row & 255, mt = row >> 8;
    const int q = (c >> 3) ^ ((r >> 1) & 3);
    const size_t byteoff = (size_t)r * 64 + q * 16 + (c & 7) * 2;
    float4 v = *(const float4*)(wrow + (size_t)row * DIMK + c0);
    float vv[4] = {v.x, v.y, v.z, v.w};
    us4 hv, lv;
#pragma unroll
    for (int i = 0; i < 4; i++) {
      unsigned short hb = f32_to_bf16_rne(vv[i]);
      hv[i] = hb;
      lv[i] = f32_to_bf16_rne(vv[i] - bf16_bits_to_f32(hb));
    }
    *(us4*)(base + (((size_t)(mt * 64 + kt)) << 14) + byteoff) = hv;
    *(us4*)(base + (((size_t)(mt * 64 + 32 + kt)) << 14) + byteoff) = lv;
  }
}

extern "C" void kernel_launch(void* const* d_in, const int* in_sizes, int n_in,
                              void* d_out, int out_size, void* d_ws, size_t ws_size,
                              hipStream_t stream) {
  const float* x = (const float*)d_in[0];
  const int* src = (const int*)d_in[1];
  const int* dst = (const int*)d_in[2];
  const float* Wq = (const float*)d_in[3];
  const float* bq = (const float*)d_in[4];
  const float* Wk = (const float*)d_in[5];
  const float* bk = (const float*)d_in[6];
  const float* Wv = (const float*)d_in[7];
  const float* bv = (const float*)d_in[8];
  const float* Wo = (const float*)d_in[9];
  const float* bo = (const float*)d_in[10];
  const float* ew = (const float*)d_in[11];
  const float* W1 = (const float*)d_in[12];
  const float* b1 = (const float*)d_in[13];
  const float* W2 = (const float*)d_in[14];
  const float* b2 = (const float*)d_in[15];
  float* out = (float*)d_out;

  const int E = in_sizes[1];
  const int M = BB * E;
  const int gx = (M + 255) / 256;  // m-tiles (BM=256)
  const int Mpad = gx * 256;

  char* w = (char*)d_ws;
  float* qs = (float*)w; w += (size_t)M * DIMK * 4;   // aliased by wrow later
  float* kv = (float*)w; w += (size_t)M * 2048 * 4;
  float* attn = (float*)w; w += (size_t)BB * NH * E * 4;
  int* fidx = (int*)w; w += (((size_t)E * 4) + 255) & ~(size_t)255;
  int* mark = (int*)w; w += (((size_t)E * 4) + 255) & ~(size_t)255;
  unsigned short* W1Th = (unsigned short*)w; w += 64 * 128 * 2;
  unsigned short* W1Tl = (unsigned short*)w; w += 64 * 128 * 2;
  unsigned short* Bq = (unsigned short*)w; w += (size_t)8 * 64 * 8192;
  unsigned short* Bkv = (unsigned short*)w; w += (size_t)16 * 64 * 8192;
  unsigned short* Bo = (unsigned short*)w; w += (size_t)8 * 64 * 8192;
  unsigned short* Apan = (unsigned short*)w; w += (size_t)gx * 64 * 16384;

  float* wrow = qs;  // qs dead after edge_sm

  // 1) fill output with bo
  const int total4 = BB * SS * (DIMK / 4);
  fill_out_kernel<<<2048, 256, 0, stream>>>((const float4*)bo, (float4*)out, total4);

  // 2) weight prep (one launch) + W1 split
  prep_w4<<<dim3(16, 16, 4), 256, 0, stream>>>(Wq, Wk, Wv, Wo, Bq, Bkv, Bo);
  prep_w1<<<1, 256, 0, stream>>>(W1, W1Th, W1Tl);

  // 3) first-occurrence map + dup marks (single block, LDS table)
  first_occ<<<1, 1024, 0, stream>>>(src, fidx, mark, E);

  // 4) q projection (src gather): N=1024 -> nty=4, 128 blocks
  prep_a<<<Mpad, 256, 0, stream>>>(x, src, Apan, M, E);
  gemm256<0><<<gx * 4, 512, 0, stream>>>(Apan, Bq, bq, nullptr, qs, DIMK, 4,
                                         nullptr, nullptr, M, E);

  // 5) fused k|v projection (dst gather): N=2048 -> nty=8, 256 blocks
  prep_a<<<Mpad, 256, 0, stream>>>(x, dst, Apan, M, E);
  gemm256<0><<<gx * 8, 512, 0, stream>>>(Apan, Bkv, bk, bv, kv, 2048, 8,
                                         nullptr, nullptr, M, E);

  // 6) edge MLP + softmax + edge_weight, fused (scores stay in LDS)
  edge_sm<<<BB * NH, 256, 0, stream>>>(qs, kv, 2048, W1Th, W1Tl, b1, W2, b2, ew, attn, E);

  // 7) weighted rows + split panels; fold duplicates; re-split affected rows
  weight_split<<<Mpad, 256, 0, stream>>>(kv + 1024, 2048, attn, wrow, Apan, M, E);
  dup_add<<<E, 256, 0, stream>>>(fidx, wrow, E);
  dup_fix<<<E, 256, 0, stream>>>(fidx, mark, wrow, Apan, E);

  // 8) final GEMM: wrow @ Wo, guarded scatter-store
  gemm256<1><<<gx * 4, 512, 0, stream>>>(Apan, Bo, bo, nullptr, out, DIMK, 4,
                                         fidx, src, M, E);
}

// Round 8
// 420.485 us; speedup vs baseline: 1.3026x; 1.3026x over previous
//
#include <hip/hip_runtime.h>
#include <hip/hip_bf16.h>
#include <math.h>

#define DIMK 1024
#define NH 16
#define HD 64
#define BB 4
#define SS 8192
#define EPAD 136
#define NT 96  // K' = 3072 / BK=32

typedef __attribute__((ext_vector_type(8))) short bf16x8;
typedef __attribute__((ext_vector_type(8))) unsigned short ushort8;
typedef __attribute__((ext_vector_type(4))) unsigned short us4;
typedef __attribute__((ext_vector_type(4))) float f32x4;

#define MFMA16(a, b, c) __builtin_amdgcn_mfma_f32_16x16x32_bf16((a), (b), (c), 0, 0, 0)

__device__ __forceinline__ unsigned short f32_to_bf16_rne(float f) {
  unsigned int u = __float_as_uint(f);
  u = (u + 0x7fffu + ((u >> 16) & 1u)) >> 16;
  return (unsigned short)u;
}
__device__ __forceinline__ float bf16_bits_to_f32(unsigned short b) {
  return __uint_as_float(((unsigned int)b) << 16);
}
__device__ __forceinline__ void gload16(const void* g, void* l) {
  __builtin_amdgcn_global_load_lds((const __attribute__((address_space(1))) void*)g,
                                   (__attribute__((address_space(3))) void*)l, 16, 0, 0);
}

// ---------------- fill d_out with bo broadcast ----------------
__global__ __launch_bounds__(256) void fill_out_kernel(const float4* __restrict__ bo4,
                                                       float4* __restrict__ out, int total4) {
  for (int i = blockIdx.x * 256 + threadIdx.x; i < total4; i += gridDim.x * 256)
    out[i] = bo4[i & 255];
}

// ---------------- W [k][n] fp32 -> tiled+swizzled bf16 hi/lo panels (all 4 weights) ----------------
__global__ __launch_bounds__(256) void prep_w4(
    const float* __restrict__ Wq, const float* __restrict__ Wk,
    const float* __restrict__ Wv, const float* __restrict__ Wo,
    unsigned short* __restrict__ Bq, unsigned short* __restrict__ Bkv,
    unsigned short* __restrict__ Bo) {
  const float* W;
  unsigned short* Bpan;
  int pnoff;
  switch (blockIdx.z) {
    case 0: W = Wq; Bpan = Bq; pnoff = 0; break;
    case 1: W = Wk; Bpan = Bkv; pnoff = 0; break;
    case 2: W = Wv; Bpan = Bkv; pnoff = 8; break;
    default: W = Wo; Bpan = Bo; pnoff = 0; break;
  }
  __shared__ float st[64][65];
  const int bk = blockIdx.x * 64, bn = blockIdx.y * 64;
  const int t = threadIdx.x;
  const int lr = t >> 4, lc = (t & 15) * 4;
#pragma unroll
  for (int i = 0; i < 4; i++) {
    int k = lr + i * 16;
    float4 v = *(const float4*)(W + (size_t)(bk + k) * DIMK + bn + lc);
    st[k][lc] = v.x; st[k][lc + 1] = v.y; st[k][lc + 2] = v.z; st[k][lc + 3] = v.w;
  }
  __syncthreads();
  const int ktile = (bk + lc) >> 5, c = lc & 31;
#pragma unroll
  for (int i = 0; i < 4; i++) {
    const int nl = lr + i * 16;
    const int n = bn + nl;
    const int r = n & 127, pn = (n >> 7) + pnoff;
    const int q = (c >> 3) ^ ((r >> 1) & 3);
    const size_t byteoff = (size_t)r * 64 + q * 16 + (c & 7) * 2;
    us4 hv, lv;
#pragma unroll
    for (int j = 0; j < 4; j++) {
      float v = st[lc + j][nl];
      unsigned short hb = f32_to_bf16_rne(v);
      hv[j] = hb;
      lv[j] = f32_to_bf16_rne(v - bf16_bits_to_f32(hb));
    }
    char* base = (char*)Bpan;
    *(us4*)(base + (((size_t)pn * 64 + ktile) << 13) + byteoff) = hv;
    *(us4*)(base + (((size_t)pn * 64 + 32 + ktile) << 13) + byteoff) = lv;
  }
}

// ---------------- split W1 [128][64] fp32 -> W1T hi/lo [64][128] bf16 ----------------
__global__ __launch_bounds__(256) void prep_w1(const float* __restrict__ W1,
                                               unsigned short* __restrict__ W1Th,
                                               unsigned short* __restrict__ W1Tl) {
  for (int idx = threadIdx.x; idx < 128 * 64; idx += 256) {
    int k = idx >> 6, n = idx & 63;
    float v = W1[idx];
    unsigned short hb = f32_to_bf16_rne(v);
    W1Th[n * 128 + k] = hb;
    W1Tl[n * 128 + k] = f32_to_bf16_rne(v - bf16_bits_to_f32(hb));
  }
}

// ---------------- gather rows of X -> tiled+swizzled bf16 hi/lo A panels ----------------
__global__ __launch_bounds__(256) void prep_a(const float* __restrict__ X,
                                              const int* __restrict__ gidx,
                                              unsigned short* __restrict__ Apan, int M, int E) {
  const int row = blockIdx.x;  // < Mpad
  const int r = row & 255, mt = row >> 8;
  const int c0 = threadIdx.x * 4;
  const int kt = c0 >> 5, c = c0 & 31;
  const int q = (c >> 3) ^ ((r >> 1) & 3);
  const size_t byteoff = (size_t)r * 64 + q * 16 + (c & 7) * 2;
  char* base = (char*)Apan;
  us4 hv = (us4){0, 0, 0, 0}, lv = (us4){0, 0, 0, 0};
  if (row < M) {
    const float* sr;
    if (gidx) {
      int b = row / E, e = row - b * E;
      sr = X + ((size_t)b * SS + gidx[e]) * DIMK;
    } else {
      sr = X + (size_t)row * DIMK;
    }
    float4 v = *(const float4*)(sr + c0);
    float vv[4] = {v.x, v.y, v.z, v.w};
#pragma unroll
    for (int i = 0; i < 4; i++) {
      unsigned short hb = f32_to_bf16_rne(vv[i]);
      hv[i] = hb;
      lv[i] = f32_to_bf16_rne(vv[i] - bf16_bits_to_f32(hb));
    }
  }
  *(us4*)(base + (((size_t)(mt * 64 + kt)) << 14) + byteoff) = hv;
  *(us4*)(base + (((size_t)(mt * 64 + 32 + kt)) << 14) + byteoff) = lv;
}

// ---------------- first-occurrence map, single block, LDS table ----------------
__global__ __launch_bounds__(1024) void first_occ(const int* __restrict__ src,
                                                  int* __restrict__ fidx,
                                                  int* __restrict__ mark, int E) {
  __shared__ int tbl[SS];
  for (int i = threadIdx.x; i < SS; i += 1024) tbl[i] = 0x7fffffff;
  __syncthreads();
  for (int e = threadIdx.x; e < E; e += 1024) atomicMin(&tbl[src[e]], e);
  __syncthreads();
  for (int e = threadIdx.x; e < E; e += 1024) mark[e] = 0;
  __syncthreads();
  for (int e = threadIdx.x; e < E; e += 1024) {
    int f = tbl[src[e]];
    fidx[e] = f;
    if (f != e) mark[f] = 1;
  }
}

// ---------------- deep-pipelined K-concat bf16 GEMM (R6-proven core) ----------------
// C[M][N] = A'(K'=3072) @ B'. 256xBN tile, BK=32, 8 waves, 4 LDS buffers,
// counted vmcnt (never drain in steady state), global_load_lds w16, swizzled panels.
template <int BN, int MODE>
__global__ __launch_bounds__(512, 2) void gemm8(
    const unsigned short* __restrict__ Apan, const unsigned short* __restrict__ Bpan,
    const float* __restrict__ bias, const float* __restrict__ bias2,
    float* __restrict__ out, int ldc, int nty,
    const int* __restrict__ fidx, const int* __restrict__ srci, int M, int E) {
  constexpr int NF = BN / 64;
  constexpr int BTILE = BN * 32;
  __shared__ unsigned short ldsA[4][8192];
  __shared__ unsigned short ldsB[4][BTILE];

  const int tid = threadIdx.x, lane = tid & 63, wv = tid >> 6;
  const int wr = wv >> 2, wc = wv & 3;

  const int w = (blockIdx.x & 7) * ((int)gridDim.x >> 3) + ((int)blockIdx.x >> 3);
  const int mt = w / nty, nt_ = w - mt * nty;
  const int m0 = mt * 256, n0 = nt_ * BN;

  const int rr = lane & 15, lq = lane >> 4;
  const int swz = (rr >> 1) & 3;
  const int aoff = (wr * 128 + rr) * 32 + ((lq ^ swz) << 3);
  const int boff = (wc * (BN / 4) + rr) * 32 + ((lq ^ swz) << 3);

  const char* Apb = (const char*)Apan + ((size_t)(mt * 64) << 14);
  const char* Bpb = (const char*)Bpan;
  const int stoff = wv * 1024 + lane * 16;

  f32x4 acc[8][NF];
#pragma unroll
  for (int i = 0; i < 8; i++)
#pragma unroll
    for (int j = 0; j < NF; j++) acc[i][j] = (f32x4){0.f, 0.f, 0.f, 0.f};

  auto stageA = [&](int kt, int buf) {
    const int apk = kt < 64 ? kt : kt - 64;  // A' = [Ah | Al | Ah]
    const char* s = Apb + ((size_t)apk << 14) + stoff;
    gload16(s, &ldsA[buf][wv * 512]);
    gload16(s + 8192, &ldsA[buf][wv * 512 + 4096]);
  };
  auto stageB = [&](int kt, int buf) {
    const int bpk = kt < 32 ? kt : kt - 32;  // B' = [Bh ; Bh ; Bl]
    if (BN == 256) {
      const char* s0 = Bpb + (((size_t)(2 * nt_) * 64 + bpk) << 13) + stoff;
      const char* s1 = Bpb + (((size_t)(2 * nt_ + 1) * 64 + bpk) << 13) + stoff;
      gload16(s0, &ldsB[buf][wv * 512]);
      gload16(s1, &ldsB[buf][wv * 512 + 4096]);
    } else {
      const char* s0 = Bpb + (((size_t)nt_ * 64 + bpk) << 13) + stoff;
      gload16(s0, &ldsB[buf][wv * 512]);
    }
  };

  stageA(0, 0); stageB(0, 0);
  stageA(1, 1); stageB(1, 1);
  stageA(2, 2); stageB(2, 2);
  if constexpr (BN == 256) asm volatile("s_waitcnt vmcnt(8)" ::: "memory");
  else asm volatile("s_waitcnt vmcnt(6)" ::: "memory");
  __builtin_amdgcn_sched_barrier(0);
  __builtin_amdgcn_s_barrier();

  for (int kt = 0; kt < NT; ++kt) {
    const int buf = kt & 3;
    const unsigned short* Al = ldsA[buf];
    const unsigned short* Bl = ldsB[buf];
    const int sb = (kt + 3) & 3;
    const bool st = (kt + 3 < NT);

    bf16x8 fb[NF];
#pragma unroll
    for (int nf = 0; nf < NF; ++nf) fb[nf] = *(const bf16x8*)(Bl + boff + nf * 512);
    bf16x8 fa[4];
#pragma unroll
    for (int mf = 0; mf < 4; ++mf) fa[mf] = *(const bf16x8*)(Al + aoff + mf * 512);
    if (st) stageA(kt + 3, sb);
#pragma unroll
    for (int mf = 0; mf < 4; ++mf)
#pragma unroll
      for (int nf = 0; nf < NF; ++nf) acc[mf][nf] = MFMA16(fa[mf], fb[nf], acc[mf][nf]);

    bf16x8 fa2[4];
#pragma unroll
    for (int mf = 0; mf < 4; ++mf) fa2[mf] = *(const bf16x8*)(Al + aoff + (mf + 4) * 512);
    if (st) stageB(kt + 3, sb);
#pragma unroll
    for (int mf = 0; mf < 4; ++mf)
#pragma unroll
      for (int nf = 0; nf < NF; ++nf) acc[mf + 4][nf] = MFMA16(fa2[mf], fb[nf], acc[mf + 4][nf]);

    if (kt < NT - 1) {
      if (kt + 3 < NT) {
        if constexpr (BN == 256) asm volatile("s_waitcnt vmcnt(8)" ::: "memory");
        else asm volatile("s_waitcnt vmcnt(6)" ::: "memory");
      } else if (kt + 2 < NT) {
        if constexpr (BN == 256) asm volatile("s_waitcnt vmcnt(4)" ::: "memory");
        else asm volatile("s_waitcnt vmcnt(3)" ::: "memory");
      } else {
        asm volatile("s_waitcnt vmcnt(0)" ::: "memory");
      }
      __builtin_amdgcn_sched_barrier(0);
      __builtin_amdgcn_s_barrier();
    }
  }

  const int cq = lane >> 4, cr = lane & 15;
#pragma unroll
  for (int nf = 0; nf < NF; ++nf) {
    const int col = n0 + wc * (BN / 4) + nf * 16 + cr;
    const float bv = (MODE == 0 && bias2 != nullptr && col >= DIMK) ? bias2[col - DIMK]
                                                                    : bias[col & (DIMK - 1)];
#pragma unroll
    for (int mf = 0; mf < 8; ++mf) {
#pragma unroll
      for (int r = 0; r < 4; ++r) {
        const int mrow = m0 + wr * 128 + mf * 16 + cq * 4 + r;
        if (mrow >= M) continue;
        if (MODE == 0) {
          out[(size_t)mrow * ldc + col] = acc[mf][nf][r] + bv;
        } else {
          int b = mrow / E, e = mrow - b * E;
          if (fidx[e] == e) {
            int orow = b * SS + srci[e];
            out[(size_t)orow * ldc + col] = acc[mf][nf][r] + bv;
          }
        }
      }
    }
  }
}

// ---------------- edge MLP scores via MFMA (R5-proven, wide grid) ----------------
__global__ __launch_bounds__(256) void edge_scores_mfma(
    const float* __restrict__ qs, const float* __restrict__ kd, int ldk,
    const unsigned short* __restrict__ W1Th, const unsigned short* __restrict__ W1Tl,
    const float* __restrict__ b1, const float* __restrict__ W2,
    const float* __restrict__ b2, float* __restrict__ scores, int E, int CH) {
  __shared__ unsigned short W1h[64][EPAD], W1l[64][EPAD];
  __shared__ unsigned short EFh[4][16][EPAD], EFl[4][16][EPAD];
  const int tid = threadIdx.x, lane = tid & 63, w = tid >> 6;
  const int bh = blockIdx.x / CH, ch = blockIdx.x - bh * CH;
  const int b = bh >> 4, h = bh & 15;

  for (int idx = tid; idx < 64 * 16; idx += 256) {
    int n = idx >> 4, g = (idx & 15) * 8;
    *(ushort8*)&W1h[n][g] = *(const ushort8*)(W1Th + n * 128 + g);
    *(ushort8*)&W1l[n][g] = *(const ushort8*)(W1Tl + n * 128 + g);
  }
  __syncthreads();

  const int etile = ch * 4 + w;
  const int e0 = etile * 16;
  if (e0 >= E) return;

  const int r = lane >> 2, c0 = (lane & 3) * 16;
  {
    const int er = (e0 + r < E) ? e0 + r : E - 1;
    const float* qrow = qs + ((size_t)(b * E + er)) * DIMK + h * HD + c0;
    const float* krow = kd + ((size_t)(b * E + er)) * (size_t)ldk + h * HD + c0;
    float qv[16], kvv[16];
#pragma unroll
    for (int i = 0; i < 4; i++) {
      *(float4*)&qv[i * 4] = *(const float4*)(qrow + i * 4);
      *(float4*)&kvv[i * 4] = *(const float4*)(krow + i * 4);
    }
    ushort8 qh[2], ql[2], kh[2], kl[2];
#pragma unroll
    for (int g = 0; g < 2; g++)
#pragma unroll
      for (int i = 0; i < 8; i++) {
        float v = qv[g * 8 + i];
        unsigned short hb = f32_to_bf16_rne(v);
        qh[g][i] = hb;
        ql[g][i] = f32_to_bf16_rne(v - bf16_bits_to_f32(hb));
        float v2 = kvv[g * 8 + i];
        unsigned short hb2 = f32_to_bf16_rne(v2);
        kh[g][i] = hb2;
        kl[g][i] = f32_to_bf16_rne(v2 - bf16_bits_to_f32(hb2));
      }
    *(ushort8*)&EFh[w][r][c0] = qh[0];
    *(ushort8*)&EFh[w][r][c0 + 8] = qh[1];
    *(ushort8*)&EFl[w][r][c0] = ql[0];
    *(ushort8*)&EFl[w][r][c0 + 8] = ql[1];
    *(ushort8*)&EFh[w][r][64 + c0] = kh[0];
    *(ushort8*)&EFh[w][r][64 + c0 + 8] = kh[1];
    *(ushort8*)&EFl[w][r][64 + c0] = kl[0];
    *(ushort8*)&EFl[w][r][64 + c0 + 8] = kl[1];
  }
  asm volatile("s_waitcnt lgkmcnt(0)" ::: "memory");
  __builtin_amdgcn_sched_barrier(0);

  f32x4 acc[4];
#pragma unroll
  for (int i = 0; i < 4; i++) acc[i] = (f32x4){0.f, 0.f, 0.f, 0.f};

  const int kk = (lane >> 4) * 8, rrl = lane & 15;
#pragma unroll
  for (int ks = 0; ks < 4; ks++) {
    bf16x8 ah = *(bf16x8*)&EFh[w][rrl][ks * 32 + kk];
    bf16x8 al = *(bf16x8*)&EFl[w][rrl][ks * 32 + kk];
#pragma unroll
    for (int nf = 0; nf < 4; nf++) {
      bf16x8 bh_ = *(bf16x8*)&W1h[nf * 16 + rrl][ks * 32 + kk];
      bf16x8 bl_ = *(bf16x8*)&W1l[nf * 16 + rrl][ks * 32 + kk];
      acc[nf] = MFMA16(ah, bh_, acc[nf]);
      acc[nf] = MFMA16(ah, bl_, acc[nf]);
      acc[nf] = MFMA16(al, bh_, acc[nf]);
    }
  }

  const int col_l = lane & 15, rq = lane >> 4;
  float w2v[4], b1v[4];
#pragma unroll
  for (int nf = 0; nf < 4; nf++) {
    w2v[nf] = W2[nf * 16 + col_l];
    b1v[nf] = b1[nf * 16 + col_l];
  }
  float p[4];
#pragma unroll
  for (int rr2 = 0; rr2 < 4; rr2++) {
    float s = 0.f;
#pragma unroll
    for (int nf = 0; nf < 4; nf++) {
      float hv = acc[nf][rr2] + b1v[nf];
      hv = 0.5f * hv * (1.f + erff(hv * 0.70710678118654752f));
      s = fmaf(hv, w2v[nf], s);
    }
    p[rr2] = s;
  }
#pragma unroll
  for (int off = 1; off < 16; off <<= 1)
#pragma unroll
    for (int rr2 = 0; rr2 < 4; rr2++) p[rr2] += __shfl_xor(p[rr2], off, 64);

  if (col_l == 0) {
    const float b2v = b2[0];
#pragma unroll
    for (int rr2 = 0; rr2 < 4; rr2++) {
      int e = e0 + rq * 4 + rr2;
      if (e < E) scores[(size_t)(b * NH + h) * E + e] = (p[rr2] + b2v) * 0.125f;
    }
  }
}

// ---------------- softmax over E per (b,h), then *= edge_weight[h] ----------------
__global__ __launch_bounds__(256) void softmax_ew(float* __restrict__ scores,
                                                  const float* __restrict__ ew, int E) {
  const int row = blockIdx.x;
  const int h = row & (NH - 1);
  float* s = scores + (size_t)row * E;
  const int tid = threadIdx.x, lane = tid & 63, w = tid >> 6;
  __shared__ float red[4];

  float vals[8];
  float mx = -1e30f;
#pragma unroll
  for (int i = 0; i < 8; i++) {
    int j = tid + i * 256;
    vals[i] = (j < E) ? s[j] : -1e30f;
    mx = fmaxf(mx, vals[i]);
  }
#pragma unroll
  for (int off = 32; off; off >>= 1) mx = fmaxf(mx, __shfl_xor(mx, off, 64));
  if (lane == 0) red[w] = mx;
  __syncthreads();
  mx = fmaxf(fmaxf(red[0], red[1]), fmaxf(red[2], red[3]));
  __syncthreads();

  float sum = 0.f;
#pragma unroll
  for (int i = 0; i < 8; i++) {
    vals[i] = __expf(vals[i] - mx);
    if (tid + i * 256 < E) sum += vals[i];
  }
#pragma unroll
  for (int off = 32; off; off >>= 1) sum += __shfl_xor(sum, off, 64);
  if (lane == 0) red[w] = sum;
  __syncthreads();
  sum = red[0] + red[1] + red[2] + red[3];

  const float scaleout = ew[h] / sum;
#pragma unroll
  for (int i = 0; i < 8; i++) {
    int j = tid + i * 256;
    if (j < E) s[j] = vals[i] * scaleout;
  }
}

// ---------------- weight rows (attn * v) + write fp32 wrow + split A panels ----------------
__global__ __launch_bounds__(256) void weight_split(
    const float* __restrict__ vd, int ldv, const float* __restrict__ attn,
    float* __restrict__ wrow, unsigned short* __restrict__ Apan, int M, int E) {
  const int row = blockIdx.x;  // < Mpad
  const int r = row & 255, mt = row >> 8;
  const int c0 = threadIdx.x * 4;
  const int kt = c0 >> 5, c = c0 & 31;
  const int q = (c >> 3) ^ ((r >> 1) & 3);
  const size_t byteoff = (size_t)r * 64 + q * 16 + (c & 7) * 2;
  char* base = (char*)Apan;
  us4 hv = (us4){0, 0, 0, 0}, lv = (us4){0, 0, 0, 0};
  if (row < M) {
    const int b = row / E, e = row - b * E;
    const float a = attn[(size_t)(b * NH + (c0 >> 6)) * E + e];
    float4 v = *(const float4*)(vd + (size_t)row * ldv + c0);
    v.x *= a; v.y *= a; v.z *= a; v.w *= a;
    *(float4*)(wrow + (size_t)row * DIMK + c0) = v;
    float vv[4] = {v.x, v.y, v.z, v.w};
#pragma unroll
    for (int i = 0; i < 4; i++) {
      unsigned short hb = f32_to_bf16_rne(vv[i]);
      hv[i] = hb;
      lv[i] = f32_to_bf16_rne(vv[i] - bf16_bits_to_f32(hb));
    }
  }
  *(us4*)(base + (((size_t)(mt * 64 + kt)) << 14) + byteoff) = hv;
  *(us4*)(base + (((size_t)(mt * 64 + 32 + kt)) << 14) + byteoff) = lv;
}

// ---------------- fold duplicate-src edges into primary rows (fp32 wrow) ----------------
__global__ __launch_bounds__(256) void dup_add(const int* __restrict__ f,
                                               float* __restrict__ wrow, int E) {
  const int e = blockIdx.x;
  const int fe = f[e];
  if (fe == e) return;
  const int d = threadIdx.x * 4;
#pragma unroll
  for (int b = 0; b < BB; b++) {
    const float4 v = *(const float4*)(wrow + (size_t)(b * E + e) * DIMK + d);
    float* dst = wrow + (size_t)(b * E + fe) * DIMK + d;
    atomicAdd(dst + 0, v.x);
    atomicAdd(dst + 1, v.y);
    atomicAdd(dst + 2, v.z);
    atomicAdd(dst + 3, v.w);
  }
}

// ---------------- re-split panels for primary rows that received duplicates ----------------
__global__ __launch_bounds__(256) void dup_fix(const int* __restrict__ fidx,
                                               const int* __restrict__ mark,
                                               const float* __restrict__ wrow,
                                               unsigned short* __restrict__ Apan, int E) {
  const int e = blockIdx.x;
  if (fidx[e] != e || !mark[e]) return;
  const int c0 = threadIdx.x * 4;
  const int kt = c0 >> 5, c = c0 & 31;
  char* base = (char*)Apan;
  for (int b = 0; b < BB; b++) {
    const int row = b * E + e;
    const int r = row & 255, mt = row >> 8;
    const int q = (c >> 3) ^ ((r >> 1) & 3);
    const size_t byteoff = (size_t)r * 64 + q * 16 + (c & 7) * 2;
    float4 v = *(const float4*)(wrow + (size_t)row * DIMK + c0);
    float vv[4] = {v.x, v.y, v.z, v.w};
    us4 hv, lv;
#pragma unroll
    for (int i = 0; i < 4; i++) {
      unsigned short hb = f32_to_bf16_rne(vv[i]);
      hv[i] = hb;
      lv[i] = f32_to_bf16_rne(vv[i] - bf16_bits_to_f32(hb));
    }
    *(us4*)(base + (((size_t)(mt * 64 + kt)) << 14) + byteoff) = hv;
    *(us4*)(base + (((size_t)(mt * 64 + 32 + kt)) << 14) + byteoff) = lv;
  }
}

extern "C" void kernel_launch(void* const* d_in, const int* in_sizes, int n_in,
                              void* d_out, int out_size, void* d_ws, size_t ws_size,
                              hipStream_t stream) {
  const float* x = (const float*)d_in[0];
  const int* src = (const int*)d_in[1];
  const int* dst = (const int*)d_in[2];
  const float* Wq = (const float*)d_in[3];
  const float* bq = (const float*)d_in[4];
  const float* Wk = (const float*)d_in[5];
  const float* bk = (const float*)d_in[6];
  const float* Wv = (const float*)d_in[7];
  const float* bv = (const float*)d_in[8];
  const float* Wo = (const float*)d_in[9];
  const float* bo = (const float*)d_in[10];
  const float* ew = (const float*)d_in[11];
  const float* W1 = (const float*)d_in[12];
  const float* b1 = (const float*)d_in[13];
  const float* W2 = (const float*)d_in[14];
  const float* b2 = (const float*)d_in[15];
  float* out = (float*)d_out;

  const int E = in_sizes[1];
  const int M = BB * E;
  const int gx = (M + 255) / 256;  // m-tiles (BM=256)
  const int Mpad = gx * 256;

  char* w = (char*)d_ws;
  float* qs = (float*)w; w += (size_t)M * DIMK * 4;   // aliased by wrow later
  float* kv = (float*)w; w += (size_t)M * 2048 * 4;
  float* sc = (float*)w; w += (size_t)BB * NH * E * 4;
  int* fidx = (int*)w; w += (((size_t)E * 4) + 255) & ~(size_t)255;
  int* mark = (int*)w; w += (((size_t)E * 4) + 255) & ~(size_t)255;
  unsigned short* W1Th = (unsigned short*)w; w += 64 * 128 * 2;
  unsigned short* W1Tl = (unsigned short*)w; w += 64 * 128 * 2;
  unsigned short* Bq = (unsigned short*)w; w += (size_t)8 * 64 * 8192;
  unsigned short* Bkv = (unsigned short*)w; w += (size_t)16 * 64 * 8192;
  unsigned short* Bo = (unsigned short*)w; w += (size_t)8 * 64 * 8192;
  unsigned short* Apan = (unsigned short*)w; w += (size_t)gx * 64 * 16384;

  float* wrow = qs;  // qs dead after edge MLP

  // 1) fill output with bo
  const int total4 = BB * SS * (DIMK / 4);
  fill_out_kernel<<<2048, 256, 0, stream>>>((const float4*)bo, (float4*)out, total4);

  // 2) weight prep (one launch) + W1 split
  prep_w4<<<dim3(16, 16, 4), 256, 0, stream>>>(Wq, Wk, Wv, Wo, Bq, Bkv, Bo);
  prep_w1<<<1, 256, 0, stream>>>(W1, W1Th, W1Tl);

  // 3) first-occurrence map + dup marks
  first_occ<<<1, 1024, 0, stream>>>(src, fidx, mark, E);

  // 4) q projection (src gather): BN=128, grid 256 (full machine)
  prep_a<<<Mpad, 256, 0, stream>>>(x, src, Apan, M, E);
  gemm8<128, 0><<<gx * 8, 512, 0, stream>>>(Apan, Bq, bq, nullptr, qs, DIMK, 8,
                                            nullptr, nullptr, M, E);

  // 5) fused k|v projection (dst gather): BN=256, grid 256
  prep_a<<<Mpad, 256, 0, stream>>>(x, dst, Apan, M, E);
  gemm8<256, 0><<<gx * 8, 512, 0, stream>>>(Apan, Bkv, bk, bv, kv, 2048, 8,
                                            nullptr, nullptr, M, E);

  // 6) edge MLP -> scores (wide grid), then softmax + edge_weight
  const int etiles = (E + 15) / 16;
  const int CH = (etiles + 3) / 4;
  edge_scores_mfma<<<BB * NH * CH, 256, 0, stream>>>(qs, kv, 2048, W1Th, W1Tl, b1, W2, b2,
                                                     sc, E, CH);
  softmax_ew<<<BB * NH, 256, 0, stream>>>(sc, ew, E);

  // 7) weighted rows + split panels; fold duplicates; re-split affected rows
  weight_split<<<Mpad, 256, 0, stream>>>(kv + 1024, 2048, sc, wrow, Apan, M, E);
  dup_add<<<E, 256, 0, stream>>>(fidx, wrow, E);
  dup_fix<<<E, 256, 0, stream>>>(fidx, mark, wrow, Apan, E);

  // 8) final GEMM: wrow @ Wo, guarded scatter-store (BN=128, grid 256)
  gemm8<128, 1><<<gx * 8, 512, 0, stream>>>(Apan, Bo, bo, nullptr, out, DIMK, 8,
                                            fidx, src, M, E);
}

// Round 9
// 386.570 us; speedup vs baseline: 1.4169x; 1.0877x over previous
//
#include <hip/hip_runtime.h>
#include <hip/hip_bf16.h>
#include <math.h>

#define DIMK 1024
#define NH 16
#define HD 64
#define BB 4
#define SS 8192
#define EPAD 136
#define NT 96  // K' = 3072 / BK=32

typedef __attribute__((ext_vector_type(8))) short bf16x8;
typedef __attribute__((ext_vector_type(8))) unsigned short ushort8;
typedef __attribute__((ext_vector_type(4))) unsigned short us4;
typedef __attribute__((ext_vector_type(4))) float f32x4;

#define MFMA16(a, b, c) __builtin_amdgcn_mfma_f32_16x16x32_bf16((a), (b), (c), 0, 0, 0)

__device__ __forceinline__ unsigned short f32_to_bf16_rne(float f) {
  unsigned int u = __float_as_uint(f);
  u = (u + 0x7fffu + ((u >> 16) & 1u)) >> 16;
  return (unsigned short)u;
}
__device__ __forceinline__ float bf16_bits_to_f32(unsigned short b) {
  return __uint_as_float(((unsigned int)b) << 16);
}
__device__ __forceinline__ void gload16(const void* g, void* l) {
  __builtin_amdgcn_global_load_lds((const __attribute__((address_space(1))) void*)g,
                                   (__attribute__((address_space(3))) void*)l, 16, 0, 0);
}

// ---------------- fill d_out with bo broadcast ----------------
__global__ __launch_bounds__(256) void fill_out_kernel(const float4* __restrict__ bo4,
                                                       float4* __restrict__ out, int total4) {
  for (int i = blockIdx.x * 256 + threadIdx.x; i < total4; i += gridDim.x * 256)
    out[i] = bo4[i & 255];
}

// ---------------- W [k][n] fp32 -> tiled+swizzled bf16 hi/lo panels (all 4 weights) ----------------
__global__ __launch_bounds__(256) void prep_w4(
    const float* __restrict__ Wq, const float* __restrict__ Wk,
    const float* __restrict__ Wv, const float* __restrict__ Wo,
    unsigned short* __restrict__ Bq, unsigned short* __restrict__ Bkv,
    unsigned short* __restrict__ Bo) {
  const float* W;
  unsigned short* Bpan;
  int pnoff;
  switch (blockIdx.z) {
    case 0: W = Wq; Bpan = Bq; pnoff = 0; break;
    case 1: W = Wk; Bpan = Bkv; pnoff = 0; break;
    case 2: W = Wv; Bpan = Bkv; pnoff = 8; break;
    default: W = Wo; Bpan = Bo; pnoff = 0; break;
  }
  __shared__ float st[64][65];
  const int bk = blockIdx.x * 64, bn = blockIdx.y * 64;
  const int t = threadIdx.x;
  const int lr = t >> 4, lc = (t & 15) * 4;
#pragma unroll
  for (int i = 0; i < 4; i++) {
    int k = lr + i * 16;
    float4 v = *(const float4*)(W + (size_t)(bk + k) * DIMK + bn + lc);
    st[k][lc] = v.x; st[k][lc + 1] = v.y; st[k][lc + 2] = v.z; st[k][lc + 3] = v.w;
  }
  __syncthreads();
  const int ktile = (bk + lc) >> 5, c = lc & 31;
#pragma unroll
  for (int i = 0; i < 4; i++) {
    const int nl = lr + i * 16;
    const int n = bn + nl;
    const int r = n & 127, pn = (n >> 7) + pnoff;
    const int q = (c >> 3) ^ ((r >> 1) & 3);
    const size_t byteoff = (size_t)r * 64 + q * 16 + (c & 7) * 2;
    us4 hv, lv;
#pragma unroll
    for (int j = 0; j < 4; j++) {
      float v = st[lc + j][nl];
      unsigned short hb = f32_to_bf16_rne(v);
      hv[j] = hb;
      lv[j] = f32_to_bf16_rne(v - bf16_bits_to_f32(hb));
    }
    char* base = (char*)Bpan;
    *(us4*)(base + (((size_t)pn * 64 + ktile) << 13) + byteoff) = hv;
    *(us4*)(base + (((size_t)pn * 64 + 32 + ktile) << 13) + byteoff) = lv;
  }
}

// ---------------- split W1 [128][64] fp32 -> W1T hi/lo [64][128] bf16 ----------------
__global__ __launch_bounds__(256) void prep_w1(const float* __restrict__ W1,
                                               unsigned short* __restrict__ W1Th,
                                               unsigned short* __restrict__ W1Tl) {
  for (int idx = threadIdx.x; idx < 128 * 64; idx += 256) {
    int k = idx >> 6, n = idx & 63;
    float v = W1[idx];
    unsigned short hb = f32_to_bf16_rne(v);
    W1Th[n * 128 + k] = hb;
    W1Tl[n * 128 + k] = f32_to_bf16_rne(v - bf16_bits_to_f32(hb));
  }
}

// ---------------- gather rows of X -> tiled+swizzled bf16 hi/lo A panels ----------------
__global__ __launch_bounds__(256) void prep_a(const float* __restrict__ X,
                                              const int* __restrict__ gidx,
                                              unsigned short* __restrict__ Apan, int M, int E) {
  const int row = blockIdx.x;  // < Mpad
  const int r = row & 255, mt = row >> 8;
  const int c0 = threadIdx.x * 4;
  const int kt = c0 >> 5, c = c0 & 31;
  const int q = (c >> 3) ^ ((r >> 1) & 3);
  const size_t byteoff = (size_t)r * 64 + q * 16 + (c & 7) * 2;
  char* base = (char*)Apan;
  us4 hv = (us4){0, 0, 0, 0}, lv = (us4){0, 0, 0, 0};
  if (row < M) {
    const float* sr;
    if (gidx) {
      int b = row / E, e = row - b * E;
      sr = X + ((size_t)b * SS + gidx[e]) * DIMK;
    } else {
      sr = X + (size_t)row * DIMK;
    }
    float4 v = *(const float4*)(sr + c0);
    float vv[4] = {v.x, v.y, v.z, v.w};
#pragma unroll
    for (int i = 0; i < 4; i++) {
      unsigned short hb = f32_to_bf16_rne(vv[i]);
      hv[i] = hb;
      lv[i] = f32_to_bf16_rne(vv[i] - bf16_bits_to_f32(hb));
    }
  }
  *(us4*)(base + (((size_t)(mt * 64 + kt)) << 14) + byteoff) = hv;
  *(us4*)(base + (((size_t)(mt * 64 + 32 + kt)) << 14) + byteoff) = lv;
}

// ---------------- first-occurrence map, single block, LDS table ----------------
__global__ __launch_bounds__(1024) void first_occ(const int* __restrict__ src,
                                                  int* __restrict__ fidx,
                                                  int* __restrict__ mark, int E) {
  __shared__ int tbl[SS];
  for (int i = threadIdx.x; i < SS; i += 1024) tbl[i] = 0x7fffffff;
  __syncthreads();
  for (int e = threadIdx.x; e < E; e += 1024) atomicMin(&tbl[src[e]], e);
  __syncthreads();
  for (int e = threadIdx.x; e < E; e += 1024) mark[e] = 0;
  __syncthreads();
  for (int e = threadIdx.x; e < E; e += 1024) {
    int f = tbl[src[e]];
    fidx[e] = f;
    if (f != e) mark[f] = 1;
  }
}

// ---------------- deep-pipelined K-concat bf16 GEMM with fragment-read prefetch ----------------
// 256xBN tile, BK=32, 8 waves, 4 LDS buffers, counted vmcnt staging (3-ahead),
// and ds_read of tile kt+1's fragments issued BEFORE MFMA of tile kt (double reg sets),
// so LDS-pipe issue overlaps matrix-pipe issue instead of serializing epochs.
template <int BN, int MODE>
__global__ __launch_bounds__(512, 2) void gemm8(
    const unsigned short* __restrict__ Apan, const unsigned short* __restrict__ Bpan,
    const float* __restrict__ bias, const float* __restrict__ bias2,
    float* __restrict__ out, int ldc, int nty,
    const int* __restrict__ fidx, const int* __restrict__ srci, int M, int E) {
  constexpr int NF = BN / 64;
  constexpr int BTILE = BN * 32;
  // loads per tile: A=2, B = (BN==256?2:1)
  constexpr int VM2 = (BN == 256) ? 8 : 6;  // 2 tiles outstanding allowed
  constexpr int VM1 = (BN == 256) ? 4 : 3;  // 1 tile outstanding allowed
  __shared__ unsigned short ldsA[4][8192];
  __shared__ unsigned short ldsB[4][BTILE];

  const int tid = threadIdx.x, lane = tid & 63, wv = tid >> 6;
  const int wr = wv >> 2, wc = wv & 3;

  const int w = (blockIdx.x & 7) * ((int)gridDim.x >> 3) + ((int)blockIdx.x >> 3);
  const int mt = w / nty, nt_ = w - mt * nty;
  const int m0 = mt * 256, n0 = nt_ * BN;

  const int rr = lane & 15, lq = lane >> 4;
  const int swz = (rr >> 1) & 3;
  const int aoff = (wr * 128 + rr) * 32 + ((lq ^ swz) << 3);
  const int boff = (wc * (BN / 4) + rr) * 32 + ((lq ^ swz) << 3);

  const char* Apb = (const char*)Apan + ((size_t)(mt * 64) << 14);
  const char* Bpb = (const char*)Bpan;
  const int stoff = wv * 1024 + lane * 16;

  f32x4 acc[8][NF];
#pragma unroll
  for (int i = 0; i < 8; i++)
#pragma unroll
    for (int j = 0; j < NF; j++) acc[i][j] = (f32x4){0.f, 0.f, 0.f, 0.f};

  auto stageA = [&](int kt) {
    const int apk = kt < 64 ? kt : kt - 64;  // A' = [Ah | Al | Ah]
    const char* s = Apb + ((size_t)apk << 14) + stoff;
    gload16(s, &ldsA[kt & 3][wv * 512]);
    gload16(s + 8192, &ldsA[kt & 3][wv * 512 + 4096]);
  };
  auto stageB = [&](int kt) {
    const int bpk = kt < 32 ? kt : kt - 32;  // B' = [Bh ; Bh ; Bl]
    if (BN == 256) {
      const char* s0 = Bpb + (((size_t)(2 * nt_) * 64 + bpk) << 13) + stoff;
      const char* s1 = Bpb + (((size_t)(2 * nt_ + 1) * 64 + bpk) << 13) + stoff;
      gload16(s0, &ldsB[kt & 3][wv * 512]);
      gload16(s1, &ldsB[kt & 3][wv * 512 + 4096]);
    } else {
      const char* s0 = Bpb + (((size_t)nt_ * 64 + bpk) << 13) + stoff;
      gload16(s0, &ldsB[kt & 3][wv * 512]);
    }
  };
  auto readFrags = [&](int kt, bf16x8* fa, bf16x8* fb) {
    const unsigned short* Al = ldsA[kt & 3];
    const unsigned short* Bl = ldsB[kt & 3];
#pragma unroll
    for (int nf = 0; nf < NF; ++nf) fb[nf] = *(const bf16x8*)(Bl + boff + nf * 512);
#pragma unroll
    for (int mf = 0; mf < 8; ++mf) fa[mf] = *(const bf16x8*)(Al + aoff + mf * 512);
  };
  auto doMFMA = [&](bf16x8* fa, bf16x8* fb) {
    __builtin_amdgcn_s_setprio(1);
#pragma unroll
    for (int mf = 0; mf < 8; ++mf)
#pragma unroll
      for (int nf = 0; nf < NF; ++nf) acc[mf][nf] = MFMA16(fa[mf], fb[nf], acc[mf][nf]);
    __builtin_amdgcn_s_setprio(0);
  };

  bf16x8 faA[8], fbA[NF], faB[8], fbB[NF];

  // prologue: stage tiles 0,1,2; ensure tile 0 landed; read tile-0 frags
  stageA(0); stageB(0);
  stageA(1); stageB(1);
  stageA(2); stageB(2);
  asm volatile("s_waitcnt vmcnt(%0)" ::"i"(VM2) : "memory");
  __builtin_amdgcn_sched_barrier(0);
  __builtin_amdgcn_s_barrier();
  readFrags(0, faA, fbA);

  for (int kt = 0; kt < NT; kt += 2) {
    // ---- even half: compute kt (setA), prefetch frags kt+1 (setB) ----
    if (kt + 3 < NT) { stageA(kt + 3); stageB(kt + 3); }
    asm volatile("s_waitcnt lgkmcnt(0)" ::: "memory");  // setA reads done (cross-wave safety)
    if (kt + 3 < NT) {
      asm volatile("s_waitcnt vmcnt(%0)" ::"i"(VM2) : "memory");  // tile kt+1 landed
    } else if (kt + 2 < NT) {
      asm volatile("s_waitcnt vmcnt(%0)" ::"i"(VM1) : "memory");
    } else {
      asm volatile("s_waitcnt vmcnt(0)" ::: "memory");
    }
    __builtin_amdgcn_sched_barrier(0);
    __builtin_amdgcn_s_barrier();
    readFrags(kt + 1, faB, fbB);  // kt+1 <= NT-1 always (NT even)
    doMFMA(faA, fbA);

    // ---- odd half: compute kt+1 (setB), prefetch frags kt+2 (setA) ----
    if (kt + 4 < NT) { stageA(kt + 4); stageB(kt + 4); }
    asm volatile("s_waitcnt lgkmcnt(0)" ::: "memory");  // setB reads done
    if (kt + 4 < NT) {
      asm volatile("s_waitcnt vmcnt(%0)" ::"i"(VM2) : "memory");  // tile kt+2 landed
    } else if (kt + 3 < NT) {
      asm volatile("s_waitcnt vmcnt(%0)" ::"i"(VM1) : "memory");
    } else {
      asm volatile("s_waitcnt vmcnt(0)" ::: "memory");
    }
    __builtin_amdgcn_sched_barrier(0);
    __builtin_amdgcn_s_barrier();
    if (kt + 2 < NT) readFrags(kt + 2, faA, fbA);
    doMFMA(faB, fbB);
  }

  const int cq = lane >> 4, cr = lane & 15;
#pragma unroll
  for (int nf = 0; nf < NF; ++nf) {
    const int col = n0 + wc * (BN / 4) + nf * 16 + cr;
    const float bv = (MODE == 0 && bias2 != nullptr && col >= DIMK) ? bias2[col - DIMK]
                                                                    : bias[col & (DIMK - 1)];
#pragma unroll
    for (int mf = 0; mf < 8; ++mf) {
#pragma unroll
      for (int r = 0; r < 4; ++r) {
        const int mrow = m0 + wr * 128 + mf * 16 + cq * 4 + r;
        if (mrow >= M) continue;
        if (MODE == 0) {
          out[(size_t)mrow * ldc + col] = acc[mf][nf][r] + bv;
        } else {
          int b = mrow / E, e = mrow - b * E;
          if (fidx[e] == e) {
            int orow = b * SS + srci[e];
            out[(size_t)orow * ldc + col] = acc[mf][nf][r] + bv;
          }
        }
      }
    }
  }
}

// ---------------- edge MLP scores via MFMA (wide grid) ----------------
__global__ __launch_bounds__(256) void edge_scores_mfma(
    const float* __restrict__ qs, const float* __restrict__ kd, int ldk,
    const unsigned short* __restrict__ W1Th, const unsigned short* __restrict__ W1Tl,
    const float* __restrict__ b1, const float* __restrict__ W2,
    const float* __restrict__ b2, float* __restrict__ scores, int E, int CH) {
  __shared__ unsigned short W1h[64][EPAD], W1l[64][EPAD];
  __shared__ unsigned short EFh[4][16][EPAD], EFl[4][16][EPAD];
  const int tid = threadIdx.x, lane = tid & 63, w = tid >> 6;
  const int bh = blockIdx.x / CH, ch = blockIdx.x - bh * CH;
  const int b = bh >> 4, h = bh & 15;

  for (int idx = tid; idx < 64 * 16; idx += 256) {
    int n = idx >> 4, g = (idx & 15) * 8;
    *(ushort8*)&W1h[n][g] = *(const ushort8*)(W1Th + n * 128 + g);
    *(ushort8*)&W1l[n][g] = *(const ushort8*)(W1Tl + n * 128 + g);
  }
  __syncthreads();

  const int etile = ch * 4 + w;
  const int e0 = etile * 16;
  if (e0 >= E) return;

  const int r = lane >> 2, c0 = (lane & 3) * 16;
  {
    const int er = (e0 + r < E) ? e0 + r : E - 1;
    const float* qrow = qs + ((size_t)(b * E + er)) * DIMK + h * HD + c0;
    const float* krow = kd + ((size_t)(b * E + er)) * (size_t)ldk + h * HD + c0;
    float qv[16], kvv[16];
#pragma unroll
    for (int i = 0; i < 4; i++) {
      *(float4*)&qv[i * 4] = *(const float4*)(qrow + i * 4);
      *(float4*)&kvv[i * 4] = *(const float4*)(krow + i * 4);
    }
    ushort8 qh[2], ql[2], kh[2], kl[2];
#pragma unroll
    for (int g = 0; g < 2; g++)
#pragma unroll
      for (int i = 0; i < 8; i++) {
        float v = qv[g * 8 + i];
        unsigned short hb = f32_to_bf16_rne(v);
        qh[g][i] = hb;
        ql[g][i] = f32_to_bf16_rne(v - bf16_bits_to_f32(hb));
        float v2 = kvv[g * 8 + i];
        unsigned short hb2 = f32_to_bf16_rne(v2);
        kh[g][i] = hb2;
        kl[g][i] = f32_to_bf16_rne(v2 - bf16_bits_to_f32(hb2));
      }
    *(ushort8*)&EFh[w][r][c0] = qh[0];
    *(ushort8*)&EFh[w][r][c0 + 8] = qh[1];
    *(ushort8*)&EFl[w][r][c0] = ql[0];
    *(ushort8*)&EFl[w][r][c0 + 8] = ql[1];
    *(ushort8*)&EFh[w][r][64 + c0] = kh[0];
    *(ushort8*)&EFh[w][r][64 + c0 + 8] = kh[1];
    *(ushort8*)&EFl[w][r][64 + c0] = kl[0];
    *(ushort8*)&EFl[w][r][64 + c0 + 8] = kl[1];
  }
  asm volatile("s_waitcnt lgkmcnt(0)" ::: "memory");
  __builtin_amdgcn_sched_barrier(0);

  f32x4 acc[4];
#pragma unroll
  for (int i = 0; i < 4; i++) acc[i] = (f32x4){0.f, 0.f, 0.f, 0.f};

  const int kk = (lane >> 4) * 8, rrl = lane & 15;
#pragma unroll
  for (int ks = 0; ks < 4; ks++) {
    bf16x8 ah = *(bf16x8*)&EFh[w][rrl][ks * 32 + kk];
    bf16x8 al = *(bf16x8*)&EFl[w][rrl][ks * 32 + kk];
#pragma unroll
    for (int nf = 0; nf < 4; nf++) {
      bf16x8 bh_ = *(bf16x8*)&W1h[nf * 16 + rrl][ks * 32 + kk];
      bf16x8 bl_ = *(bf16x8*)&W1l[nf * 16 + rrl][ks * 32 + kk];
      acc[nf] = MFMA16(ah, bh_, acc[nf]);
      acc[nf] = MFMA16(ah, bl_, acc[nf]);
      acc[nf] = MFMA16(al, bh_, acc[nf]);
    }
  }

  const int col_l = lane & 15, rq = lane >> 4;
  float w2v[4], b1v[4];
#pragma unroll
  for (int nf = 0; nf < 4; nf++) {
    w2v[nf] = W2[nf * 16 + col_l];
    b1v[nf] = b1[nf * 16 + col_l];
  }
  float p[4];
#pragma unroll
  for (int rr2 = 0; rr2 < 4; rr2++) {
    float s = 0.f;
#pragma unroll
    for (int nf = 0; nf < 4; nf++) {
      float hv = acc[nf][rr2] + b1v[nf];
      hv = 0.5f * hv * (1.f + erff(hv * 0.70710678118654752f));
      s = fmaf(hv, w2v[nf], s);
    }
    p[rr2] = s;
  }
#pragma unroll
  for (int off = 1; off < 16; off <<= 1)
#pragma unroll
    for (int rr2 = 0; rr2 < 4; rr2++) p[rr2] += __shfl_xor(p[rr2], off, 64);

  if (col_l == 0) {
    const float b2v = b2[0];
#pragma unroll
    for (int rr2 = 0; rr2 < 4; rr2++) {
      int e = e0 + rq * 4 + rr2;
      if (e < E) scores[(size_t)(b * NH + h) * E + e] = (p[rr2] + b2v) * 0.125f;
    }
  }
}

// ---------------- softmax over E per (b,h), then *= edge_weight[h] ----------------
__global__ __launch_bounds__(256) void softmax_ew(float* __restrict__ scores,
                                                  const float* __restrict__ ew, int E) {
  const int row = blockIdx.x;
  const int h = row & (NH - 1);
  float* s = scores + (size_t)row * E;
  const int tid = threadIdx.x, lane = tid & 63, w = tid >> 6;
  __shared__ float red[4];

  float vals[8];
  float mx = -1e30f;
#pragma unroll
  for (int i = 0; i < 8; i++) {
    int j = tid + i * 256;
    vals[i] = (j < E) ? s[j] : -1e30f;
    mx = fmaxf(mx, vals[i]);
  }
#pragma unroll
  for (int off = 32; off; off >>= 1) mx = fmaxf(mx, __shfl_xor(mx, off, 64));
  if (lane == 0) red[w] = mx;
  __syncthreads();
  mx = fmaxf(fmaxf(red[0], red[1]), fmaxf(red[2], red[3]));
  __syncthreads();

  float sum = 0.f;
#pragma unroll
  for (int i = 0; i < 8; i++) {
    vals[i] = __expf(vals[i] - mx);
    if (tid + i * 256 < E) sum += vals[i];
  }
#pragma unroll
  for (int off = 32; off; off >>= 1) sum += __shfl_xor(sum, off, 64);
  if (lane == 0) red[w] = sum;
  __syncthreads();
  sum = red[0] + red[1] + red[2] + red[3];

  const float scaleout = ew[h] / sum;
#pragma unroll
  for (int i = 0; i < 8; i++) {
    int j = tid + i * 256;
    if (j < E) s[j] = vals[i] * scaleout;
  }
}

// ---------------- weight rows (attn * v) + write fp32 wrow + split A panels ----------------
__global__ __launch_bounds__(256) void weight_split(
    const float* __restrict__ vd, int ldv, const float* __restrict__ attn,
    float* __restrict__ wrow, unsigned short* __restrict__ Apan, int M, int E) {
  const int row = blockIdx.x;  // < Mpad
  const int r = row & 255, mt = row >> 8;
  const int c0 = threadIdx.x * 4;
  const int kt = c0 >> 5, c = c0 & 31;
  const int q = (c >> 3) ^ ((r >> 1) & 3);
  const size_t byteoff = (size_t)r * 64 + q * 16 + (c & 7) * 2;
  char* base = (char*)Apan;
  us4 hv = (us4){0, 0, 0, 0}, lv = (us4){0, 0, 0, 0};
  if (row < M) {
    const int b = row / E, e = row - b * E;
    const float a = attn[(size_t)(b * NH + (c0 >> 6)) * E + e];
    float4 v = *(const float4*)(vd + (size_t)row * ldv + c0);
    v.x *= a; v.y *= a; v.z *= a; v.w *= a;
    *(float4*)(wrow + (size_t)row * DIMK + c0) = v;
    float vv[4] = {v.x, v.y, v.z, v.w};
#pragma unroll
    for (int i = 0; i < 4; i++) {
      unsigned short hb = f32_to_bf16_rne(vv[i]);
      hv[i] = hb;
      lv[i] = f32_to_bf16_rne(vv[i] - bf16_bits_to_f32(hb));
    }
  }
  *(us4*)(base + (((size_t)(mt * 64 + kt)) << 14) + byteoff) = hv;
  *(us4*)(base + (((size_t)(mt * 64 + 32 + kt)) << 14) + byteoff) = lv;
}

// ---------------- fold duplicate-src edges into primary rows (fp32 wrow) ----------------
__global__ __launch_bounds__(256) void dup_add(const int* __restrict__ f,
                                               float* __restrict__ wrow, int E) {
  const int e = blockIdx.x;
  const int fe = f[e];
  if (fe == e) return;
  const int d = threadIdx.x * 4;
#pragma unroll
  for (int b = 0; b < BB; b++) {
    const float4 v = *(const float4*)(wrow + (size_t)(b * E + e) * DIMK + d);
    float* dst = wrow + (size_t)(b * E + fe) * DIMK + d;
    atomicAdd(dst + 0, v.x);
    atomicAdd(dst + 1, v.y);
    atomicAdd(dst + 2, v.z);
    atomicAdd(dst + 3, v.w);
  }
}

// ---------------- re-split panels for primary rows that received duplicates ----------------
__global__ __launch_bounds__(256) void dup_fix(const int* __restrict__ fidx,
                                               const int* __restrict__ mark,
                                               const float* __restrict__ wrow,
                                               unsigned short* __restrict__ Apan, int E) {
  const int e = blockIdx.x;
  if (fidx[e] != e || !mark[e]) return;
  const int c0 = threadIdx.x * 4;
  const int kt = c0 >> 5, c = c0 & 31;
  char* base = (char*)Apan;
  for (int b = 0; b < BB; b++) {
    const int row = b * E + e;
    const int r = row & 255, mt = row >> 8;
    const int q = (c >> 3) ^ ((r >> 1) & 3);
    const size_t byteoff = (size_t)r * 64 + q * 16 + (c & 7) * 2;
    float4 v = *(const float4*)(wrow + (size_t)row * DIMK + c0);
    float vv[4] = {v.x, v.y, v.z, v.w};
    us4 hv, lv;
#pragma unroll
    for (int i = 0; i < 4; i++) {
      unsigned short hb = f32_to_bf16_rne(vv[i]);
      hv[i] = hb;
      lv[i] = f32_to_bf16_rne(vv[i] - bf16_bits_to_f32(hb));
    }
    *(us4*)(base + (((size_t)(mt * 64 + kt)) << 14) + byteoff) = hv;
    *(us4*)(base + (((size_t)(mt * 64 + 32 + kt)) << 14) + byteoff) = lv;
  }
}

extern "C" void kernel_launch(void* const* d_in, const int* in_sizes, int n_in,
                              void* d_out, int out_size, void* d_ws, size_t ws_size,
                              hipStream_t stream) {
  const float* x = (const float*)d_in[0];
  const int* src = (const int*)d_in[1];
  const int* dst = (const int*)d_in[2];
  const float* Wq = (const float*)d_in[3];
  const float* bq = (const float*)d_in[4];
  const float* Wk = (const float*)d_in[5];
  const float* bk = (const float*)d_in[6];
  const float* Wv = (const float*)d_in[7];
  const float* bv = (const float*)d_in[8];
  const float* Wo = (const float*)d_in[9];
  const float* bo = (const float*)d_in[10];
  const float* ew = (const float*)d_in[11];
  const float* W1 = (const float*)d_in[12];
  const float* b1 = (const float*)d_in[13];
  const float* W2 = (const float*)d_in[14];
  const float* b2 = (const float*)d_in[15];
  float* out = (float*)d_out;

  const int E = in_sizes[1];
  const int M = BB * E;
  const int gx = (M + 255) / 256;  // m-tiles (BM=256)
  const int Mpad = gx * 256;

  char* w = (char*)d_ws;
  float* qs = (float*)w; w += (size_t)M * DIMK * 4;   // aliased by wrow later
  float* kv = (float*)w; w += (size_t)M * 2048 * 4;
  float* sc = (float*)w; w += (size_t)BB * NH * E * 4;
  int* fidx = (int*)w; w += (((size_t)E * 4) + 255) & ~(size_t)255;
  int* mark = (int*)w; w += (((size_t)E * 4) + 255) & ~(size_t)255;
  unsigned short* W1Th = (unsigned short*)w; w += 64 * 128 * 2;
  unsigned short* W1Tl = (unsigned short*)w; w += 64 * 128 * 2;
  unsigned short* Bq = (unsigned short*)w; w += (size_t)8 * 64 * 8192;
  unsigned short* Bkv = (unsigned short*)w; w += (size_t)16 * 64 * 8192;
  unsigned short* Bo = (unsigned short*)w; w += (size_t)8 * 64 * 8192;
  unsigned short* Apan = (unsigned short*)w; w += (size_t)gx * 64 * 16384;

  float* wrow = qs;  // qs dead after edge MLP

  // 1) fill output with bo
  const int total4 = BB * SS * (DIMK / 4);
  fill_out_kernel<<<2048, 256, 0, stream>>>((const float4*)bo, (float4*)out, total4);

  // 2) weight prep (one launch) + W1 split
  prep_w4<<<dim3(16, 16, 4), 256, 0, stream>>>(Wq, Wk, Wv, Wo, Bq, Bkv, Bo);
  prep_w1<<<1, 256, 0, stream>>>(W1, W1Th, W1Tl);

  // 3) first-occurrence map + dup marks
  first_occ<<<1, 1024, 0, stream>>>(src, fidx, mark, E);

  // 4) q projection (src gather): BN=128, grid 256 (full machine)
  prep_a<<<Mpad, 256, 0, stream>>>(x, src, Apan, M, E);
  gemm8<128, 0><<<gx * 8, 512, 0, stream>>>(Apan, Bq, bq, nullptr, qs, DIMK, 8,
                                            nullptr, nullptr, M, E);

  // 5) fused k|v projection (dst gather): BN=256, grid 256
  prep_a<<<Mpad, 256, 0, stream>>>(x, dst, Apan, M, E);
  gemm8<256, 0><<<gx * 8, 512, 0, stream>>>(Apan, Bkv, bk, bv, kv, 2048, 8,
                                            nullptr, nullptr, M, E);

  // 6) edge MLP -> scores (wide grid), then softmax + edge_weight
  const int etiles = (E + 15) / 16;
  const int CH = (etiles + 3) / 4;
  edge_scores_mfma<<<BB * NH * CH, 256, 0, stream>>>(qs, kv, 2048, W1Th, W1Tl, b1, W2, b2,
                                                     sc, E, CH);
  softmax_ew<<<BB * NH, 256, 0, stream>>>(sc, ew, E);

  // 7) weighted rows + split panels; fold duplicates; re-split affected rows
  weight_split<<<Mpad, 256, 0, stream>>>(kv + 1024, 2048, sc, wrow, Apan, M, E);
  dup_add<<<E, 256, 0, stream>>>(fidx, wrow, E);
  dup_fix<<<E, 256, 0, stream>>>(fidx, mark, wrow, Apan, E);

  // 8) final GEMM: wrow @ Wo, guarded scatter-store (BN=128, grid 256)
  gemm8<128, 1><<<gx * 8, 512, 0, stream>>>(Apan, Bo, bo, nullptr, out, DIMK, 8,
                                            fidx, src, M, E);
}

// Round 10
// 350.066 us; speedup vs baseline: 1.5646x; 1.1043x over previous
//
#include <hip/hip_runtime.h>
#include <hip/hip_bf16.h>
#include <math.h>

#define DIMK 1024
#define NH 16
#define HD 64
#define BB 4
#define SS 8192
#define EPAD 136
#define NKT 32  // original K 1024 / BK=32

typedef __attribute__((ext_vector_type(8))) short bf16x8;
typedef __attribute__((ext_vector_type(8))) unsigned short ushort8;
typedef __attribute__((ext_vector_type(4))) unsigned short us4;
typedef __attribute__((ext_vector_type(4))) float f32x4;

#define MFMA16(a, b, c) __builtin_amdgcn_mfma_f32_16x16x32_bf16((a), (b), (c), 0, 0, 0)

__device__ __forceinline__ unsigned short f32_to_bf16_rne(float f) {
  unsigned int u = __float_as_uint(f);
  u = (u + 0x7fffu + ((u >> 16) & 1u)) >> 16;
  return (unsigned short)u;
}
__device__ __forceinline__ float bf16_bits_to_f32(unsigned short b) {
  return __uint_as_float(((unsigned int)b) << 16);
}
__device__ __forceinline__ void gload16(const void* g, void* l) {
  __builtin_amdgcn_global_load_lds((const __attribute__((address_space(1))) void*)g,
                                   (__attribute__((address_space(3))) void*)l, 16, 0, 0);
}

// ---------------- fill d_out with bo broadcast ----------------
__global__ __launch_bounds__(256) void fill_out_kernel(const float4* __restrict__ bo4,
                                                       float4* __restrict__ out, int total4) {
  for (int i = blockIdx.x * 256 + threadIdx.x; i < total4; i += gridDim.x * 256)
    out[i] = bo4[i & 255];
}

// ---------------- W [k][n] fp32 -> tiled+swizzled bf16 hi/lo panels (all 4 weights) ----------------
__global__ __launch_bounds__(256) void prep_w4(
    const float* __restrict__ Wq, const float* __restrict__ Wk,
    const float* __restrict__ Wv, const float* __restrict__ Wo,
    unsigned short* __restrict__ Bq, unsigned short* __restrict__ Bkv,
    unsigned short* __restrict__ Bo) {
  const float* W;
  unsigned short* Bpan;
  int pnoff;
  switch (blockIdx.z) {
    case 0: W = Wq; Bpan = Bq; pnoff = 0; break;
    case 1: W = Wk; Bpan = Bkv; pnoff = 0; break;
    case 2: W = Wv; Bpan = Bkv; pnoff = 8; break;
    default: W = Wo; Bpan = Bo; pnoff = 0; break;
  }
  __shared__ float st[64][65];
  const int bk = blockIdx.x * 64, bn = blockIdx.y * 64;
  const int t = threadIdx.x;
  const int lr = t >> 4, lc = (t & 15) * 4;
#pragma unroll
  for (int i = 0; i < 4; i++) {
    int k = lr + i * 16;
    float4 v = *(const float4*)(W + (size_t)(bk + k) * DIMK + bn + lc);
    st[k][lc] = v.x; st[k][lc + 1] = v.y; st[k][lc + 2] = v.z; st[k][lc + 3] = v.w;
  }
  __syncthreads();
  const int ktile = (bk + lc) >> 5, c = lc & 31;
#pragma unroll
  for (int i = 0; i < 4; i++) {
    const int nl = lr + i * 16;
    const int n = bn + nl;
    const int r = n & 127, pn = (n >> 7) + pnoff;
    const int q = (c >> 3) ^ ((r >> 1) & 3);
    const size_t byteoff = (size_t)r * 64 + q * 16 + (c & 7) * 2;
    us4 hv, lv;
#pragma unroll
    for (int j = 0; j < 4; j++) {
      float v = st[lc + j][nl];
      unsigned short hb = f32_to_bf16_rne(v);
      hv[j] = hb;
      lv[j] = f32_to_bf16_rne(v - bf16_bits_to_f32(hb));
    }
    char* base = (char*)Bpan;
    *(us4*)(base + (((size_t)pn * 64 + ktile) << 13) + byteoff) = hv;
    *(us4*)(base + (((size_t)pn * 64 + 32 + ktile) << 13) + byteoff) = lv;
  }
}

// ---------------- split W1 [128][64] fp32 -> W1T hi/lo [64][128] bf16 ----------------
__global__ __launch_bounds__(256) void prep_w1(const float* __restrict__ W1,
                                               unsigned short* __restrict__ W1Th,
                                               unsigned short* __restrict__ W1Tl) {
  for (int idx = threadIdx.x; idx < 128 * 64; idx += 256) {
    int k = idx >> 6, n = idx & 63;
    float v = W1[idx];
    unsigned short hb = f32_to_bf16_rne(v);
    W1Th[n * 128 + k] = hb;
    W1Tl[n * 128 + k] = f32_to_bf16_rne(v - bf16_bits_to_f32(hb));
  }
}

// ---------------- gather rows of X -> tiled+swizzled bf16 hi/lo A panels ----------------
__global__ __launch_bounds__(256) void prep_a(const float* __restrict__ X,
                                              const int* __restrict__ gidx,
                                              unsigned short* __restrict__ Apan, int M, int E) {
  const int row = blockIdx.x;  // < Mpad
  const int r = row & 255, mt = row >> 8;
  const int c0 = threadIdx.x * 4;
  const int kt = c0 >> 5, c = c0 & 31;
  const int q = (c >> 3) ^ ((r >> 1) & 3);
  const size_t byteoff = (size_t)r * 64 + q * 16 + (c & 7) * 2;
  char* base = (char*)Apan;
  us4 hv = (us4){0, 0, 0, 0}, lv = (us4){0, 0, 0, 0};
  if (row < M) {
    const float* sr;
    if (gidx) {
      int b = row / E, e = row - b * E;
      sr = X + ((size_t)b * SS + gidx[e]) * DIMK;
    } else {
      sr = X + (size_t)row * DIMK;
    }
    float4 v = *(const float4*)(sr + c0);
    float vv[4] = {v.x, v.y, v.z, v.w};
#pragma unroll
    for (int i = 0; i < 4; i++) {
      unsigned short hb = f32_to_bf16_rne(vv[i]);
      hv[i] = hb;
      lv[i] = f32_to_bf16_rne(vv[i] - bf16_bits_to_f32(hb));
    }
  }
  *(us4*)(base + (((size_t)(mt * 64 + kt)) << 14) + byteoff) = hv;
  *(us4*)(base + (((size_t)(mt * 64 + 32 + kt)) << 14) + byteoff) = lv;
}

// ---------------- first-occurrence map, single block, LDS table ----------------
__global__ __launch_bounds__(1024) void first_occ(const int* __restrict__ src,
                                                  int* __restrict__ fidx,
                                                  int* __restrict__ mark, int E) {
  __shared__ int tbl[SS];
  for (int i = threadIdx.x; i < SS; i += 1024) tbl[i] = 0x7fffffff;
  __syncthreads();
  for (int e = threadIdx.x; e < E; e += 1024) atomicMin(&tbl[src[e]], e);
  __syncthreads();
  for (int e = threadIdx.x; e < E; e += 1024) mark[e] = 0;
  __syncthreads();
  for (int e = threadIdx.x; e < E; e += 1024) {
    int f = tbl[src[e]];
    fidx[e] = f;
    if (f != e) mark[f] = 1;
  }
}

// ---------------- fused 3-term split-bf16 GEMM ----------------
// Per original K-32 tile: stage {Ah,Al,Bh,Bl} ONCE (double-buffered), run 3 MFMA
// clusters (ah*bh, al*bh, ah*bl) from one staging. Cuts LDS reads 33% and HBM
// A-fetch 33% vs the K-concat form. Counted lgkmcnt within tile; one barrier/tile.
template <int BN, int MODE>
__global__ __launch_bounds__(512, 2) void gemm8(
    const unsigned short* __restrict__ Apan, const unsigned short* __restrict__ Bpan,
    const float* __restrict__ bias, const float* __restrict__ bias2,
    float* __restrict__ out, int ldc, int nty,
    const int* __restrict__ fidx, const int* __restrict__ srci, int M, int E) {
  constexpr int NF = BN / 64;
  constexpr int BT = BN * 32;  // ushorts per B half-tile
  __shared__ unsigned short ldsAh[2][8192];
  __shared__ unsigned short ldsAl[2][8192];
  __shared__ unsigned short ldsBh[2][BT];
  __shared__ unsigned short ldsBl[2][BT];

  const int tid = threadIdx.x, lane = tid & 63, wv = tid >> 6;
  const int wr = wv >> 2, wc = wv & 3;

  const int w = (blockIdx.x & 7) * ((int)gridDim.x >> 3) + ((int)blockIdx.x >> 3);
  const int mt = w / nty, nt_ = w - mt * nty;
  const int m0 = mt * 256, n0 = nt_ * BN;

  const int rr = lane & 15, lq = lane >> 4;
  const int swz = (rr >> 1) & 3;
  const int aoff = (wr * 128 + rr) * 32 + ((lq ^ swz) << 3);
  const int boff = (wc * (BN / 4) + rr) * 32 + ((lq ^ swz) << 3);

  const char* Apb = (const char*)Apan + ((size_t)(mt * 64) << 14);
  const char* Bpb = (const char*)Bpan;
  const int stoff = wv * 1024 + lane * 16;

  f32x4 acc[8][NF];
#pragma unroll
  for (int i = 0; i < 8; i++)
#pragma unroll
    for (int j = 0; j < NF; j++) acc[i][j] = (f32x4){0.f, 0.f, 0.f, 0.f};

  auto stage = [&](int kt, int buf) {
    const char* sAh = Apb + ((size_t)kt << 14) + stoff;
    const char* sAl = Apb + ((size_t)(32 + kt) << 14) + stoff;
    gload16(sAh, &ldsAh[buf][wv * 512]);
    gload16(sAh + 8192, &ldsAh[buf][wv * 512 + 4096]);
    gload16(sAl, &ldsAl[buf][wv * 512]);
    gload16(sAl + 8192, &ldsAl[buf][wv * 512 + 4096]);
    if (BN == 256) {
      const char* sB0h = Bpb + (((size_t)(2 * nt_) * 64 + kt) << 13) + stoff;
      const char* sB1h = Bpb + (((size_t)(2 * nt_ + 1) * 64 + kt) << 13) + stoff;
      const char* sB0l = Bpb + (((size_t)(2 * nt_) * 64 + 32 + kt) << 13) + stoff;
      const char* sB1l = Bpb + (((size_t)(2 * nt_ + 1) * 64 + 32 + kt) << 13) + stoff;
      gload16(sB0h, &ldsBh[buf][wv * 512]);
      gload16(sB1h, &ldsBh[buf][wv * 512 + 4096]);
      gload16(sB0l, &ldsBl[buf][wv * 512]);
      gload16(sB1l, &ldsBl[buf][wv * 512 + 4096]);
    } else {
      const char* sBh = Bpb + (((size_t)nt_ * 64 + kt) << 13) + stoff;
      const char* sBl = Bpb + (((size_t)nt_ * 64 + 32 + kt) << 13) + stoff;
      gload16(sBh, &ldsBh[buf][wv * 512]);
      gload16(sBl, &ldsBl[buf][wv * 512]);
    }
  };

  // prologue
  stage(0, 0);
  asm volatile("s_waitcnt vmcnt(0)" ::: "memory");
  __builtin_amdgcn_sched_barrier(0);
  __builtin_amdgcn_s_barrier();

  for (int kt = 0; kt < NKT; ++kt) {
    const int buf = kt & 1;
    const unsigned short* Ah = ldsAh[buf];
    const unsigned short* Al = ldsAl[buf];
    const unsigned short* Bh = ldsBh[buf];
    const unsigned short* Bl = ldsBl[buf];

    // issue fragment reads: Bh(NF), Ah(8), Al(8)
    bf16x8 fbh[NF], fah[8], fal[8], fbl[NF];
#pragma unroll
    for (int nf = 0; nf < NF; ++nf) fbh[nf] = *(const bf16x8*)(Bh + boff + nf * 512);
#pragma unroll
    for (int mf = 0; mf < 8; ++mf) fah[mf] = *(const bf16x8*)(Ah + aoff + mf * 512);
#pragma unroll
    for (int mf = 0; mf < 8; ++mf) fal[mf] = *(const bf16x8*)(Al + aoff + mf * 512);

    // stage next tile into the other buffer (covered by this tile's compute)
    if (kt + 1 < NKT) stage(kt + 1, buf ^ 1);

    // cluster 1: ah * bh (needs first NF+8 reads; allow 8 (the fal) outstanding)
    asm volatile("s_waitcnt lgkmcnt(8)" ::: "memory");
    __builtin_amdgcn_sched_barrier(0);
    __builtin_amdgcn_s_setprio(1);
#pragma unroll
    for (int mf = 0; mf < 8; ++mf)
#pragma unroll
      for (int nf = 0; nf < NF; ++nf) acc[mf][nf] = MFMA16(fah[mf], fbh[nf], acc[mf][nf]);
    __builtin_amdgcn_s_setprio(0);

    // cluster 2: al * bh
    asm volatile("s_waitcnt lgkmcnt(0)" ::: "memory");
    __builtin_amdgcn_sched_barrier(0);
    __builtin_amdgcn_s_setprio(1);
#pragma unroll
    for (int mf = 0; mf < 8; ++mf)
#pragma unroll
      for (int nf = 0; nf < NF; ++nf) acc[mf][nf] = MFMA16(fal[mf], fbh[nf], acc[mf][nf]);
    __builtin_amdgcn_s_setprio(0);

    // cluster 3: ah * bl (read Bl now; fal/fbh dead)
#pragma unroll
    for (int nf = 0; nf < NF; ++nf) fbl[nf] = *(const bf16x8*)(Bl + boff + nf * 512);
    asm volatile("s_waitcnt lgkmcnt(0)" ::: "memory");
    __builtin_amdgcn_sched_barrier(0);
    __builtin_amdgcn_s_setprio(1);
#pragma unroll
    for (int mf = 0; mf < 8; ++mf)
#pragma unroll
      for (int nf = 0; nf < NF; ++nf) acc[mf][nf] = MFMA16(fah[mf], fbl[nf], acc[mf][nf]);
    __builtin_amdgcn_s_setprio(0);

    // tile boundary: next stage landed (issued a full tile ago -> cheap), one barrier
    if (kt + 1 < NKT) {
      asm volatile("s_waitcnt vmcnt(0)" ::: "memory");
      __builtin_amdgcn_sched_barrier(0);
      __builtin_amdgcn_s_barrier();
    }
  }

  const int cq = lane >> 4, cr = lane & 15;
#pragma unroll
  for (int nf = 0; nf < NF; ++nf) {
    const int col = n0 + wc * (BN / 4) + nf * 16 + cr;
    const float bv = (MODE == 0 && bias2 != nullptr && col >= DIMK) ? bias2[col - DIMK]
                                                                    : bias[col & (DIMK - 1)];
#pragma unroll
    for (int mf = 0; mf < 8; ++mf) {
#pragma unroll
      for (int r = 0; r < 4; ++r) {
        const int mrow = m0 + wr * 128 + mf * 16 + cq * 4 + r;
        if (mrow >= M) continue;
        if (MODE == 0) {
          out[(size_t)mrow * ldc + col] = acc[mf][nf][r] + bv;
        } else {
          int b = mrow / E, e = mrow - b * E;
          if (fidx[e] == e) {
            int orow = b * SS + srci[e];
            out[(size_t)orow * ldc + col] = acc[mf][nf][r] + bv;
          }
        }
      }
    }
  }
}

// ---------------- edge MLP scores via MFMA (wide grid) ----------------
__global__ __launch_bounds__(256) void edge_scores_mfma(
    const float* __restrict__ qs, const float* __restrict__ kd, int ldk,
    const unsigned short* __restrict__ W1Th, const unsigned short* __restrict__ W1Tl,
    const float* __restrict__ b1, const float* __restrict__ W2,
    const float* __restrict__ b2, float* __restrict__ scores, int E, int CH) {
  __shared__ unsigned short W1h[64][EPAD], W1l[64][EPAD];
  __shared__ unsigned short EFh[4][16][EPAD], EFl[4][16][EPAD];
  const int tid = threadIdx.x, lane = tid & 63, w = tid >> 6;
  const int bh = blockIdx.x / CH, ch = blockIdx.x - bh * CH;
  const int b = bh >> 4, h = bh & 15;

  for (int idx = tid; idx < 64 * 16; idx += 256) {
    int n = idx >> 4, g = (idx & 15) * 8;
    *(ushort8*)&W1h[n][g] = *(const ushort8*)(W1Th + n * 128 + g);
    *(ushort8*)&W1l[n][g] = *(const ushort8*)(W1Tl + n * 128 + g);
  }
  __syncthreads();

  const int etile = ch * 4 + w;
  const int e0 = etile * 16;
  if (e0 >= E) return;

  const int r = lane >> 2, c0 = (lane & 3) * 16;
  {
    const int er = (e0 + r < E) ? e0 + r : E - 1;
    const float* qrow = qs + ((size_t)(b * E + er)) * DIMK + h * HD + c0;
    const float* krow = kd + ((size_t)(b * E + er)) * (size_t)ldk + h * HD + c0;
    float qv[16], kvv[16];
#pragma unroll
    for (int i = 0; i < 4; i++) {
      *(float4*)&qv[i * 4] = *(const float4*)(qrow + i * 4);
      *(float4*)&kvv[i * 4] = *(const float4*)(krow + i * 4);
    }
    ushort8 qh[2], ql[2], kh[2], kl[2];
#pragma unroll
    for (int g = 0; g < 2; g++)
#pragma unroll
      for (int i = 0; i < 8; i++) {
        float v = qv[g * 8 + i];
        unsigned short hb = f32_to_bf16_rne(v);
        qh[g][i] = hb;
        ql[g][i] = f32_to_bf16_rne(v - bf16_bits_to_f32(hb));
        float v2 = kvv[g * 8 + i];
        unsigned short hb2 = f32_to_bf16_rne(v2);
        kh[g][i] = hb2;
        kl[g][i] = f32_to_bf16_rne(v2 - bf16_bits_to_f32(hb2));
      }
    *(ushort8*)&EFh[w][r][c0] = qh[0];
    *(ushort8*)&EFh[w][r][c0 + 8] = qh[1];
    *(ushort8*)&EFl[w][r][c0] = ql[0];
    *(ushort8*)&EFl[w][r][c0 + 8] = ql[1];
    *(ushort8*)&EFh[w][r][64 + c0] = kh[0];
    *(ushort8*)&EFh[w][r][64 + c0 + 8] = kh[1];
    *(ushort8*)&EFl[w][r][64 + c0] = kl[0];
    *(ushort8*)&EFl[w][r][64 + c0 + 8] = kl[1];
  }
  asm volatile("s_waitcnt lgkmcnt(0)" ::: "memory");
  __builtin_amdgcn_sched_barrier(0);

  f32x4 acc[4];
#pragma unroll
  for (int i = 0; i < 4; i++) acc[i] = (f32x4){0.f, 0.f, 0.f, 0.f};

  const int kk = (lane >> 4) * 8, rrl = lane & 15;
#pragma unroll
  for (int ks = 0; ks < 4; ks++) {
    bf16x8 ah = *(bf16x8*)&EFh[w][rrl][ks * 32 + kk];
    bf16x8 al = *(bf16x8*)&EFl[w][rrl][ks * 32 + kk];
#pragma unroll
    for (int nf = 0; nf < 4; nf++) {
      bf16x8 bh_ = *(bf16x8*)&W1h[nf * 16 + rrl][ks * 32 + kk];
      bf16x8 bl_ = *(bf16x8*)&W1l[nf * 16 + rrl][ks * 32 + kk];
      acc[nf] = MFMA16(ah, bh_, acc[nf]);
      acc[nf] = MFMA16(ah, bl_, acc[nf]);
      acc[nf] = MFMA16(al, bh_, acc[nf]);
    }
  }

  const int col_l = lane & 15, rq = lane >> 4;
  float w2v[4], b1v[4];
#pragma unroll
  for (int nf = 0; nf < 4; nf++) {
    w2v[nf] = W2[nf * 16 + col_l];
    b1v[nf] = b1[nf * 16 + col_l];
  }
  float p[4];
#pragma unroll
  for (int rr2 = 0; rr2 < 4; rr2++) {
    float s = 0.f;
#pragma unroll
    for (int nf = 0; nf < 4; nf++) {
      float hv = acc[nf][rr2] + b1v[nf];
      hv = 0.5f * hv * (1.f + erff(hv * 0.70710678118654752f));
      s = fmaf(hv, w2v[nf], s);
    }
    p[rr2] = s;
  }
#pragma unroll
  for (int off = 1; off < 16; off <<= 1)
#pragma unroll
    for (int rr2 = 0; rr2 < 4; rr2++) p[rr2] += __shfl_xor(p[rr2], off, 64);

  if (col_l == 0) {
    const float b2v = b2[0];
#pragma unroll
    for (int rr2 = 0; rr2 < 4; rr2++) {
      int e = e0 + rq * 4 + rr2;
      if (e < E) scores[(size_t)(b * NH + h) * E + e] = (p[rr2] + b2v) * 0.125f;
    }
  }
}

// ---------------- softmax over E per (b,h), then *= edge_weight[h] ----------------
__global__ __launch_bounds__(256) void softmax_ew(float* __restrict__ scores,
                                                  const float* __restrict__ ew, int E) {
  const int row = blockIdx.x;
  const int h = row & (NH - 1);
  float* s = scores + (size_t)row * E;
  const int tid = threadIdx.x, lane = tid & 63, w = tid >> 6;
  __shared__ float red[4];

  float vals[8];
  float mx = -1e30f;
#pragma unroll
  for (int i = 0; i < 8; i++) {
    int j = tid + i * 256;
    vals[i] = (j < E) ? s[j] : -1e30f;
    mx = fmaxf(mx, vals[i]);
  }
#pragma unroll
  for (int off = 32; off; off >>= 1) mx = fmaxf(mx, __shfl_xor(mx, off, 64));
  if (lane == 0) red[w] = mx;
  __syncthreads();
  mx = fmaxf(fmaxf(red[0], red[1]), fmaxf(red[2], red[3]));
  __syncthreads();

  float sum = 0.f;
#pragma unroll
  for (int i = 0; i < 8; i++) {
    vals[i] = __expf(vals[i] - mx);
    if (tid + i * 256 < E) sum += vals[i];
  }
#pragma unroll
  for (int off = 32; off; off >>= 1) sum += __shfl_xor(sum, off, 64);
  if (lane == 0) red[w] = sum;
  __syncthreads();
  sum = red[0] + red[1] + red[2] + red[3];

  const float scaleout = ew[h] / sum;
#pragma unroll
  for (int i = 0; i < 8; i++) {
    int j = tid + i * 256;
    if (j < E) s[j] = vals[i] * scaleout;
  }
}

// ---------------- weight rows (attn * v) + write fp32 wrow + split A panels ----------------
__global__ __launch_bounds__(256) void weight_split(
    const float* __restrict__ vd, int ldv, const float* __restrict__ attn,
    float* __restrict__ wrow, unsigned short* __restrict__ Apan, int M, int E) {
  const int row = blockIdx.x;  // < Mpad
  const int r = row & 255, mt = row >> 8;
  const int c0 = threadIdx.x * 4;
  const int kt = c0 >> 5, c = c0 & 31;
  const int q = (c >> 3) ^ ((r >> 1) & 3);
  const size_t byteoff = (size_t)r * 64 + q * 16 + (c & 7) * 2;
  char* base = (char*)Apan;
  us4 hv = (us4){0, 0, 0, 0}, lv = (us4){0, 0, 0, 0};
  if (row < M) {
    const int b = row / E, e = row - b * E;
    const float a = attn[(size_t)(b * NH + (c0 >> 6)) * E + e];
    float4 v = *(const float4*)(vd + (size_t)row * ldv + c0);
    v.x *= a; v.y *= a; v.z *= a; v.w *= a;
    *(float4*)(wrow + (size_t)row * DIMK + c0) = v;
    float vv[4] = {v.x, v.y, v.z, v.w};
#pragma unroll
    for (int i = 0; i < 4; i++) {
      unsigned short hb = f32_to_bf16_rne(vv[i]);
      hv[i] = hb;
      lv[i] = f32_to_bf16_rne(vv[i] - bf16_bits_to_f32(hb));
    }
  }
  *(us4*)(base + (((size_t)(mt * 64 + kt)) << 14) + byteoff) = hv;
  *(us4*)(base + (((size_t)(mt * 64 + 32 + kt)) << 14) + byteoff) = lv;
}

// ---------------- fold duplicate-src edges into primary rows (fp32 wrow) ----------------
__global__ __launch_bounds__(256) void dup_add(const int* __restrict__ f,
                                               float* __restrict__ wrow, int E) {
  const int e = blockIdx.x;
  const int fe = f[e];
  if (fe == e) return;
  const int d = threadIdx.x * 4;
#pragma unroll
  for (int b = 0; b < BB; b++) {
    const float4 v = *(const float4*)(wrow + (size_t)(b * E + e) * DIMK + d);
    float* dst = wrow + (size_t)(b * E + fe) * DIMK + d;
    atomicAdd(dst + 0, v.x);
    atomicAdd(dst + 1, v.y);
    atomicAdd(dst + 2, v.z);
    atomicAdd(dst + 3, v.w);
  }
}

// ---------------- re-split panels for primary rows that received duplicates ----------------
__global__ __launch_bounds__(256) void dup_fix(const int* __restrict__ fidx,
                                               const int* __restrict__ mark,
                                               const float* __restrict__ wrow,
                                               unsigned short* __restrict__ Apan, int E) {
  const int e = blockIdx.x;
  if (fidx[e] != e || !mark[e]) return;
  const int c0 = threadIdx.x * 4;
  const int kt = c0 >> 5, c = c0 & 31;
  char* base = (char*)Apan;
  for (int b = 0; b < BB; b++) {
    const int row = b * E + e;
    const int r = row & 255, mt = row >> 8;
    const int q = (c >> 3) ^ ((r >> 1) & 3);
    const size_t byteoff = (size_t)r * 64 + q * 16 + (c & 7) * 2;
    float4 v = *(const float4*)(wrow + (size_t)row * DIMK + c0);
    float vv[4] = {v.x, v.y, v.z, v.w};
    us4 hv, lv;
#pragma unroll
    for (int i = 0; i < 4; i++) {
      unsigned short hb = f32_to_bf16_rne(vv[i]);
      hv[i] = hb;
      lv[i] = f32_to_bf16_rne(vv[i] - bf16_bits_to_f32(hb));
    }
    *(us4*)(base + (((size_t)(mt * 64 + kt)) << 14) + byteoff) = hv;
    *(us4*)(base + (((size_t)(mt * 64 + 32 + kt)) << 14) + byteoff) = lv;
  }
}

extern "C" void kernel_launch(void* const* d_in, const int* in_sizes, int n_in,
                              void* d_out, int out_size, void* d_ws, size_t ws_size,
                              hipStream_t stream) {
  const float* x = (const float*)d_in[0];
  const int* src = (const int*)d_in[1];
  const int* dst = (const int*)d_in[2];
  const float* Wq = (const float*)d_in[3];
  const float* bq = (const float*)d_in[4];
  const float* Wk = (const float*)d_in[5];
  const float* bk = (const float*)d_in[6];
  const float* Wv = (const float*)d_in[7];
  const float* bv = (const float*)d_in[8];
  const float* Wo = (const float*)d_in[9];
  const float* bo = (const float*)d_in[10];
  const float* ew = (const float*)d_in[11];
  const float* W1 = (const float*)d_in[12];
  const float* b1 = (const float*)d_in[13];
  const float* W2 = (const float*)d_in[14];
  const float* b2 = (const float*)d_in[15];
  float* out = (float*)d_out;

  const int E = in_sizes[1];
  const int M = BB * E;
  const int gx = (M + 255) / 256;  // m-tiles (BM=256)
  const int Mpad = gx * 256;

  char* w = (char*)d_ws;
  float* qs = (float*)w; w += (size_t)M * DIMK * 4;   // aliased by wrow later
  float* kv = (float*)w; w += (size_t)M * 2048 * 4;
  float* sc = (float*)w; w += (size_t)BB * NH * E * 4;
  int* fidx = (int*)w; w += (((size_t)E * 4) + 255) & ~(size_t)255;
  int* mark = (int*)w; w += (((size_t)E * 4) + 255) & ~(size_t)255;
  unsigned short* W1Th = (unsigned short*)w; w += 64 * 128 * 2;
  unsigned short* W1Tl = (unsigned short*)w; w += 64 * 128 * 2;
  unsigned short* Bq = (unsigned short*)w; w += (size_t)8 * 64 * 8192;
  unsigned short* Bkv = (unsigned short*)w; w += (size_t)16 * 64 * 8192;
  unsigned short* Bo = (unsigned short*)w; w += (size_t)8 * 64 * 8192;
  unsigned short* Apan = (unsigned short*)w; w += (size_t)gx * 64 * 16384;

  float* wrow = qs;  // qs dead after edge MLP

  // 1) fill output with bo
  const int total4 = BB * SS * (DIMK / 4);
  fill_out_kernel<<<2048, 256, 0, stream>>>((const float4*)bo, (float4*)out, total4);

  // 2) weight prep (one launch) + W1 split
  prep_w4<<<dim3(16, 16, 4), 256, 0, stream>>>(Wq, Wk, Wv, Wo, Bq, Bkv, Bo);
  prep_w1<<<1, 256, 0, stream>>>(W1, W1Th, W1Tl);

  // 3) first-occurrence map + dup marks
  first_occ<<<1, 1024, 0, stream>>>(src, fidx, mark, E);

  // 4) q projection (src gather): BN=128, grid 256 (full machine)
  prep_a<<<Mpad, 256, 0, stream>>>(x, src, Apan, M, E);
  gemm8<128, 0><<<gx * 8, 512, 0, stream>>>(Apan, Bq, bq, nullptr, qs, DIMK, 8,
                                            nullptr, nullptr, M, E);

  // 5) fused k|v projection (dst gather): BN=256, grid 256
  prep_a<<<Mpad, 256, 0, stream>>>(x, dst, Apan, M, E);
  gemm8<256, 0><<<gx * 8, 512, 0, stream>>>(Apan, Bkv, bk, bv, kv, 2048, 8,
                                            nullptr, nullptr, M, E);

  // 6) edge MLP -> scores (wide grid), then softmax + edge_weight
  const int etiles = (E + 15) / 16;
  const int CH = (etiles + 3) / 4;
  edge_scores_mfma<<<BB * NH * CH, 256, 0, stream>>>(qs, kv, 2048, W1Th, W1Tl, b1, W2, b2,
                                                     sc, E, CH);
  softmax_ew<<<BB * NH, 256, 0, stream>>>(sc, ew, E);

  // 7) weighted rows + split panels; fold duplicates; re-split affected rows
  weight_split<<<Mpad, 256, 0, stream>>>(kv + 1024, 2048, sc, wrow, Apan, M, E);
  dup_add<<<E, 256, 0, stream>>>(fidx, wrow, E);
  dup_fix<<<E, 256, 0, stream>>>(fidx, mark, wrow, Apan, E);

  // 8) final GEMM: wrow @ Wo, guarded scatter-store (BN=128, grid 256)
  gemm8<128, 1><<<gx * 8, 512, 0, stream>>>(Apan, Bo, bo, nullptr, out, DIMK, 8,
                                            fidx, src, M, E);
}

// Round 11
// 344.944 us; speedup vs baseline: 1.5878x; 1.0148x over previous
//
#include <hip/hip_runtime.h>
#include <hip/hip_bf16.h>
#include <math.h>

#define DIMK 1024
#define NH 16
#define HD 64
#define BB 4
#define SS 8192
#define EPAD 136
#define NKT 32  // original K 1024 / BK=32

typedef __attribute__((ext_vector_type(8))) short bf16x8;
typedef __attribute__((ext_vector_type(8))) unsigned short ushort8;
typedef __attribute__((ext_vector_type(4))) unsigned short us4;
typedef __attribute__((ext_vector_type(4))) float f32x4;

#define MFMA16(a, b, c) __builtin_amdgcn_mfma_f32_16x16x32_bf16((a), (b), (c), 0, 0, 0)

__device__ __forceinline__ unsigned short f32_to_bf16_rne(float f) {
  unsigned int u = __float_as_uint(f);
  u = (u + 0x7fffu + ((u >> 16) & 1u)) >> 16;
  return (unsigned short)u;
}
__device__ __forceinline__ float bf16_bits_to_f32(unsigned short b) {
  return __uint_as_float(((unsigned int)b) << 16);
}
__device__ __forceinline__ void gload16(const void* g, void* l) {
  __builtin_amdgcn_global_load_lds((const __attribute__((address_space(1))) void*)g,
                                   (__attribute__((address_space(3))) void*)l, 16, 0, 0);
}

// ---------------- fill d_out with bo broadcast ----------------
__global__ __launch_bounds__(256) void fill_out_kernel(const float4* __restrict__ bo4,
                                                       float4* __restrict__ out, int total4) {
  for (int i = blockIdx.x * 256 + threadIdx.x; i < total4; i += gridDim.x * 256)
    out[i] = bo4[i & 255];
}

// ---------------- W [k][n] fp32 -> tiled+swizzled bf16 hi/lo panels (all 4 weights) ----------------
__global__ __launch_bounds__(256) void prep_w4(
    const float* __restrict__ Wq, const float* __restrict__ Wk,
    const float* __restrict__ Wv, const float* __restrict__ Wo,
    unsigned short* __restrict__ Bq, unsigned short* __restrict__ Bkv,
    unsigned short* __restrict__ Bo) {
  const float* W;
  unsigned short* Bpan;
  int pnoff;
  switch (blockIdx.z) {
    case 0: W = Wq; Bpan = Bq; pnoff = 0; break;
    case 1: W = Wk; Bpan = Bkv; pnoff = 0; break;
    case 2: W = Wv; Bpan = Bkv; pnoff = 8; break;
    default: W = Wo; Bpan = Bo; pnoff = 0; break;
  }
  __shared__ float st[64][65];
  const int bk = blockIdx.x * 64, bn = blockIdx.y * 64;
  const int t = threadIdx.x;
  const int lr = t >> 4, lc = (t & 15) * 4;
#pragma unroll
  for (int i = 0; i < 4; i++) {
    int k = lr + i * 16;
    float4 v = *(const float4*)(W + (size_t)(bk + k) * DIMK + bn + lc);
    st[k][lc] = v.x; st[k][lc + 1] = v.y; st[k][lc + 2] = v.z; st[k][lc + 3] = v.w;
  }
  __syncthreads();
  const int ktile = (bk + lc) >> 5, c = lc & 31;
#pragma unroll
  for (int i = 0; i < 4; i++) {
    const int nl = lr + i * 16;
    const int n = bn + nl;
    const int r = n & 127, pn = (n >> 7) + pnoff;
    const int q = (c >> 3) ^ ((r >> 1) & 3);
    const size_t byteoff = (size_t)r * 64 + q * 16 + (c & 7) * 2;
    us4 hv, lv;
#pragma unroll
    for (int j = 0; j < 4; j++) {
      float v = st[lc + j][nl];
      unsigned short hb = f32_to_bf16_rne(v);
      hv[j] = hb;
      lv[j] = f32_to_bf16_rne(v - bf16_bits_to_f32(hb));
    }
    char* base = (char*)Bpan;
    *(us4*)(base + (((size_t)pn * 64 + ktile) << 13) + byteoff) = hv;
    *(us4*)(base + (((size_t)pn * 64 + 32 + ktile) << 13) + byteoff) = lv;
  }
}

// ---------------- split W1 [128][64] fp32 -> W1T hi/lo [64][128] bf16 ----------------
__global__ __launch_bounds__(256) void prep_w1(const float* __restrict__ W1,
                                               unsigned short* __restrict__ W1Th,
                                               unsigned short* __restrict__ W1Tl) {
  for (int idx = threadIdx.x; idx < 128 * 64; idx += 256) {
    int k = idx >> 6, n = idx & 63;
    float v = W1[idx];
    unsigned short hb = f32_to_bf16_rne(v);
    W1Th[n * 128 + k] = hb;
    W1Tl[n * 128 + k] = f32_to_bf16_rne(v - bf16_bits_to_f32(hb));
  }
}

// ---------------- gather rows of X -> tiled+swizzled bf16 hi/lo A panels ----------------
__global__ __launch_bounds__(256) void prep_a(const float* __restrict__ X,
                                              const int* __restrict__ gidx,
                                              unsigned short* __restrict__ Apan, int M, int E) {
  const int row = blockIdx.x;  // < Mpad
  const int r = row & 255, mt = row >> 8;
  const int c0 = threadIdx.x * 4;
  const int kt = c0 >> 5, c = c0 & 31;
  const int q = (c >> 3) ^ ((r >> 1) & 3);
  const size_t byteoff = (size_t)r * 64 + q * 16 + (c & 7) * 2;
  char* base = (char*)Apan;
  us4 hv = (us4){0, 0, 0, 0}, lv = (us4){0, 0, 0, 0};
  if (row < M) {
    const float* sr;
    if (gidx) {
      int b = row / E, e = row - b * E;
      sr = X + ((size_t)b * SS + gidx[e]) * DIMK;
    } else {
      sr = X + (size_t)row * DIMK;
    }
    float4 v = *(const float4*)(sr + c0);
    float vv[4] = {v.x, v.y, v.z, v.w};
#pragma unroll
    for (int i = 0; i < 4; i++) {
      unsigned short hb = f32_to_bf16_rne(vv[i]);
      hv[i] = hb;
      lv[i] = f32_to_bf16_rne(vv[i] - bf16_bits_to_f32(hb));
    }
  }
  *(us4*)(base + (((size_t)(mt * 64 + kt)) << 14) + byteoff) = hv;
  *(us4*)(base + (((size_t)(mt * 64 + 32 + kt)) << 14) + byteoff) = lv;
}

// ---------------- first-occurrence map, single block, LDS table ----------------
__global__ __launch_bounds__(1024) void first_occ(const int* __restrict__ src,
                                                  int* __restrict__ fidx,
                                                  int* __restrict__ mark, int E) {
  __shared__ int tbl[SS];
  for (int i = threadIdx.x; i < SS; i += 1024) tbl[i] = 0x7fffffff;
  __syncthreads();
  for (int e = threadIdx.x; e < E; e += 1024) atomicMin(&tbl[src[e]], e);
  __syncthreads();
  for (int e = threadIdx.x; e < E; e += 1024) mark[e] = 0;
  __syncthreads();
  for (int e = threadIdx.x; e < E; e += 1024) {
    int f = tbl[src[e]];
    fidx[e] = f;
    if (f != e) mark[f] = 1;
  }
}

// ---------------- fused 3-term split-bf16 GEMM, barrier hidden under C3 ----------------
// Per original K-32 tile: stage {Ah,Al,Bh,Bl} ONCE (double-buffered), all fragment
// reads issued upfront, counted lgkmcnt per cluster, and the tile's vmcnt(0)+barrier
// placed BEFORE cluster 3 so C3's MFMAs cover barrier desync and overlap the next
// tile's read burst.
template <int BN, int MODE>
__global__ __launch_bounds__(512, 2) void gemm8(
    const unsigned short* __restrict__ Apan, const unsigned short* __restrict__ Bpan,
    const float* __restrict__ bias, const float* __restrict__ bias2,
    float* __restrict__ out, int ldc, int nty,
    const int* __restrict__ fidx, const int* __restrict__ srci, int M, int E) {
  constexpr int NF = BN / 64;
  constexpr int BT = BN * 32;  // ushorts per B half-tile
  __shared__ unsigned short ldsAh[2][8192];
  __shared__ unsigned short ldsAl[2][8192];
  __shared__ unsigned short ldsBh[2][BT];
  __shared__ unsigned short ldsBl[2][BT];

  const int tid = threadIdx.x, lane = tid & 63, wv = tid >> 6;
  const int wr = wv >> 2, wc = wv & 3;

  const int w = (blockIdx.x & 7) * ((int)gridDim.x >> 3) + ((int)blockIdx.x >> 3);
  const int mt = w / nty, nt_ = w - mt * nty;
  const int m0 = mt * 256, n0 = nt_ * BN;

  const int rr = lane & 15, lq = lane >> 4;
  const int swz = (rr >> 1) & 3;
  const int aoff = (wr * 128 + rr) * 32 + ((lq ^ swz) << 3);
  const int boff = (wc * (BN / 4) + rr) * 32 + ((lq ^ swz) << 3);

  const char* Apb = (const char*)Apan + ((size_t)(mt * 64) << 14);
  const char* Bpb = (const char*)Bpan;
  const int stoff = wv * 1024 + lane * 16;

  f32x4 acc[8][NF];
#pragma unroll
  for (int i = 0; i < 8; i++)
#pragma unroll
    for (int j = 0; j < NF; j++) acc[i][j] = (f32x4){0.f, 0.f, 0.f, 0.f};

  auto stage = [&](int kt, int buf) {
    const char* sAh = Apb + ((size_t)kt << 14) + stoff;
    const char* sAl = Apb + ((size_t)(32 + kt) << 14) + stoff;
    gload16(sAh, &ldsAh[buf][wv * 512]);
    gload16(sAh + 8192, &ldsAh[buf][wv * 512 + 4096]);
    gload16(sAl, &ldsAl[buf][wv * 512]);
    gload16(sAl + 8192, &ldsAl[buf][wv * 512 + 4096]);
    if (BN == 256) {
      const char* sB0h = Bpb + (((size_t)(2 * nt_) * 64 + kt) << 13) + stoff;
      const char* sB1h = Bpb + (((size_t)(2 * nt_ + 1) * 64 + kt) << 13) + stoff;
      const char* sB0l = Bpb + (((size_t)(2 * nt_) * 64 + 32 + kt) << 13) + stoff;
      const char* sB1l = Bpb + (((size_t)(2 * nt_ + 1) * 64 + 32 + kt) << 13) + stoff;
      gload16(sB0h, &ldsBh[buf][wv * 512]);
      gload16(sB1h, &ldsBh[buf][wv * 512 + 4096]);
      gload16(sB0l, &ldsBl[buf][wv * 512]);
      gload16(sB1l, &ldsBl[buf][wv * 512 + 4096]);
    } else {
      const char* sBh = Bpb + (((size_t)nt_ * 64 + kt) << 13) + stoff;
      const char* sBl = Bpb + (((size_t)nt_ * 64 + 32 + kt) << 13) + stoff;
      gload16(sBh, &ldsBh[buf][wv * 512]);
      gload16(sBl, &ldsBl[buf][wv * 512]);
    }
  };

  // prologue
  stage(0, 0);
  asm volatile("s_waitcnt vmcnt(0)" ::: "memory");
  __builtin_amdgcn_sched_barrier(0);
  __builtin_amdgcn_s_barrier();

  for (int kt = 0; kt < NKT; ++kt) {
    const int buf = kt & 1;
    const unsigned short* Ah = ldsAh[buf];
    const unsigned short* Al = ldsAl[buf];
    const unsigned short* Bh = ldsBh[buf];
    const unsigned short* Bl = ldsBl[buf];

    // issue ALL fragment reads upfront, in pinned groups:
    // group 1 (C1 operands): fbh(NF), fah(8)
    bf16x8 fbh[NF], fah[8], fal[8], fbl[NF];
#pragma unroll
    for (int nf = 0; nf < NF; ++nf) fbh[nf] = *(const bf16x8*)(Bh + boff + nf * 512);
#pragma unroll
    for (int mf = 0; mf < 8; ++mf) fah[mf] = *(const bf16x8*)(Ah + aoff + mf * 512);
    __builtin_amdgcn_sched_barrier(0);
    // group 2 (C2 operand): fal(8)
#pragma unroll
    for (int mf = 0; mf < 8; ++mf) fal[mf] = *(const bf16x8*)(Al + aoff + mf * 512);
    __builtin_amdgcn_sched_barrier(0);
    // group 3 (C3 operand): fbl(NF)
#pragma unroll
    for (int nf = 0; nf < NF; ++nf) fbl[nf] = *(const bf16x8*)(Bl + boff + nf * 512);
    __builtin_amdgcn_sched_barrier(0);

    // stage next tile into the other buffer (covered by this tile's compute)
    if (kt + 1 < NKT) stage(kt + 1, buf ^ 1);

    // cluster 1: ah * bh (outstanding allowed: fal(8)+fbl(NF))
    asm volatile("s_waitcnt lgkmcnt(%0)" ::"i"(8 + NF) : "memory");
    __builtin_amdgcn_sched_barrier(0);
    __builtin_amdgcn_s_setprio(1);
#pragma unroll
    for (int mf = 0; mf < 8; ++mf)
#pragma unroll
      for (int nf = 0; nf < NF; ++nf) acc[mf][nf] = MFMA16(fah[mf], fbh[nf], acc[mf][nf]);
    __builtin_amdgcn_s_setprio(0);

    // cluster 2: al * bh (outstanding allowed: fbl(NF))
    asm volatile("s_waitcnt lgkmcnt(%0)" ::"i"(NF) : "memory");
    __builtin_amdgcn_sched_barrier(0);
    __builtin_amdgcn_s_setprio(1);
#pragma unroll
    for (int mf = 0; mf < 8; ++mf)
#pragma unroll
      for (int nf = 0; nf < NF; ++nf) acc[mf][nf] = MFMA16(fal[mf], fbh[nf], acc[mf][nf]);
    __builtin_amdgcn_s_setprio(0);

    // all my LDS reads done + my DMAs landed -> barrier, then C3 covers the
    // barrier shadow and overlaps the next tile's read burst.
    asm volatile("s_waitcnt lgkmcnt(0)" ::: "memory");
    if (kt + 1 < NKT) {
      asm volatile("s_waitcnt vmcnt(0)" ::: "memory");
      __builtin_amdgcn_sched_barrier(0);
      __builtin_amdgcn_s_barrier();
    } else {
      __builtin_amdgcn_sched_barrier(0);
    }

    // cluster 3: ah * bl
    __builtin_amdgcn_s_setprio(1);
#pragma unroll
    for (int mf = 0; mf < 8; ++mf)
#pragma unroll
      for (int nf = 0; nf < NF; ++nf) acc[mf][nf] = MFMA16(fah[mf], fbl[nf], acc[mf][nf]);
    __builtin_amdgcn_s_setprio(0);
  }

  const int cq = lane >> 4, cr = lane & 15;
#pragma unroll
  for (int nf = 0; nf < NF; ++nf) {
    const int col = n0 + wc * (BN / 4) + nf * 16 + cr;
    const float bv = (MODE == 0 && bias2 != nullptr && col >= DIMK) ? bias2[col - DIMK]
                                                                    : bias[col & (DIMK - 1)];
#pragma unroll
    for (int mf = 0; mf < 8; ++mf) {
#pragma unroll
      for (int r = 0; r < 4; ++r) {
        const int mrow = m0 + wr * 128 + mf * 16 + cq * 4 + r;
        if (mrow >= M) continue;
        if (MODE == 0) {
          out[(size_t)mrow * ldc + col] = acc[mf][nf][r] + bv;
        } else {
          int b = mrow / E, e = mrow - b * E;
          if (fidx[e] == e) {
            int orow = b * SS + srci[e];
            out[(size_t)orow * ldc + col] = acc[mf][nf][r] + bv;
          }
        }
      }
    }
  }
}

// ---------------- edge MLP scores via MFMA (wide grid) ----------------
__global__ __launch_bounds__(256) void edge_scores_mfma(
    const float* __restrict__ qs, const float* __restrict__ kd, int ldk,
    const unsigned short* __restrict__ W1Th, const unsigned short* __restrict__ W1Tl,
    const float* __restrict__ b1, const float* __restrict__ W2,
    const float* __restrict__ b2, float* __restrict__ scores, int E, int CH) {
  __shared__ unsigned short W1h[64][EPAD], W1l[64][EPAD];
  __shared__ unsigned short EFh[4][16][EPAD], EFl[4][16][EPAD];
  const int tid = threadIdx.x, lane = tid & 63, w = tid >> 6;
  const int bh = blockIdx.x / CH, ch = blockIdx.x - bh * CH;
  const int b = bh >> 4, h = bh & 15;

  for (int idx = tid; idx < 64 * 16; idx += 256) {
    int n = idx >> 4, g = (idx & 15) * 8;
    *(ushort8*)&W1h[n][g] = *(const ushort8*)(W1Th + n * 128 + g);
    *(ushort8*)&W1l[n][g] = *(const ushort8*)(W1Tl + n * 128 + g);
  }
  __syncthreads();

  const int etile = ch * 4 + w;
  const int e0 = etile * 16;
  if (e0 >= E) return;

  const int r = lane >> 2, c0 = (lane & 3) * 16;
  {
    const int er = (e0 + r < E) ? e0 + r : E - 1;
    const float* qrow = qs + ((size_t)(b * E + er)) * DIMK + h * HD + c0;
    const float* krow = kd + ((size_t)(b * E + er)) * (size_t)ldk + h * HD + c0;
    float qv[16], kvv[16];
#pragma unroll
    for (int i = 0; i < 4; i++) {
      *(float4*)&qv[i * 4] = *(const float4*)(qrow + i * 4);
      *(float4*)&kvv[i * 4] = *(const float4*)(krow + i * 4);
    }
    ushort8 qh[2], ql[2], kh[2], kl[2];
#pragma unroll
    for (int g = 0; g < 2; g++)
#pragma unroll
      for (int i = 0; i < 8; i++) {
        float v = qv[g * 8 + i];
        unsigned short hb = f32_to_bf16_rne(v);
        qh[g][i] = hb;
        ql[g][i] = f32_to_bf16_rne(v - bf16_bits_to_f32(hb));
        float v2 = kvv[g * 8 + i];
        unsigned short hb2 = f32_to_bf16_rne(v2);
        kh[g][i] = hb2;
        kl[g][i] = f32_to_bf16_rne(v2 - bf16_bits_to_f32(hb2));
      }
    *(ushort8*)&EFh[w][r][c0] = qh[0];
    *(ushort8*)&EFh[w][r][c0 + 8] = qh[1];
    *(ushort8*)&EFl[w][r][c0] = ql[0];
    *(ushort8*)&EFl[w][r][c0 + 8] = ql[1];
    *(ushort8*)&EFh[w][r][64 + c0] = kh[0];
    *(ushort8*)&EFh[w][r][64 + c0 + 8] = kh[1];
    *(ushort8*)&EFl[w][r][64 + c0] = kl[0];
    *(ushort8*)&EFl[w][r][64 + c0 + 8] = kl[1];
  }
  asm volatile("s_waitcnt lgkmcnt(0)" ::: "memory");
  __builtin_amdgcn_sched_barrier(0);

  f32x4 acc[4];
#pragma unroll
  for (int i = 0; i < 4; i++) acc[i] = (f32x4){0.f, 0.f, 0.f, 0.f};

  const int kk = (lane >> 4) * 8, rrl = lane & 15;
#pragma unroll
  for (int ks = 0; ks < 4; ks++) {
    bf16x8 ah = *(bf16x8*)&EFh[w][rrl][ks * 32 + kk];
    bf16x8 al = *(bf16x8*)&EFl[w][rrl][ks * 32 + kk];
#pragma unroll
    for (int nf = 0; nf < 4; nf++) {
      bf16x8 bh_ = *(bf16x8*)&W1h[nf * 16 + rrl][ks * 32 + kk];
      bf16x8 bl_ = *(bf16x8*)&W1l[nf * 16 + rrl][ks * 32 + kk];
      acc[nf] = MFMA16(ah, bh_, acc[nf]);
      acc[nf] = MFMA16(ah, bl_, acc[nf]);
      acc[nf] = MFMA16(al, bh_, acc[nf]);
    }
  }

  const int col_l = lane & 15, rq = lane >> 4;
  float w2v[4], b1v[4];
#pragma unroll
  for (int nf = 0; nf < 4; nf++) {
    w2v[nf] = W2[nf * 16 + col_l];
    b1v[nf] = b1[nf * 16 + col_l];
  }
  float p[4];
#pragma unroll
  for (int rr2 = 0; rr2 < 4; rr2++) {
    float s = 0.f;
#pragma unroll
    for (int nf = 0; nf < 4; nf++) {
      float hv = acc[nf][rr2] + b1v[nf];
      hv = 0.5f * hv * (1.f + erff(hv * 0.70710678118654752f));
      s = fmaf(hv, w2v[nf], s);
    }
    p[rr2] = s;
  }
#pragma unroll
  for (int off = 1; off < 16; off <<= 1)
#pragma unroll
    for (int rr2 = 0; rr2 < 4; rr2++) p[rr2] += __shfl_xor(p[rr2], off, 64);

  if (col_l == 0) {
    const float b2v = b2[0];
#pragma unroll
    for (int rr2 = 0; rr2 < 4; rr2++) {
      int e = e0 + rq * 4 + rr2;
      if (e < E) scores[(size_t)(b * NH + h) * E + e] = (p[rr2] + b2v) * 0.125f;
    }
  }
}

// ---------------- softmax over E per (b,h), then *= edge_weight[h] ----------------
__global__ __launch_bounds__(256) void softmax_ew(float* __restrict__ scores,
                                                  const float* __restrict__ ew, int E) {
  const int row = blockIdx.x;
  const int h = row & (NH - 1);
  float* s = scores + (size_t)row * E;
  const int tid = threadIdx.x, lane = tid & 63, w = tid >> 6;
  __shared__ float red[4];

  float vals[8];
  float mx = -1e30f;
#pragma unroll
  for (int i = 0; i < 8; i++) {
    int j = tid + i * 256;
    vals[i] = (j < E) ? s[j] : -1e30f;
    mx = fmaxf(mx, vals[i]);
  }
#pragma unroll
  for (int off = 32; off; off >>= 1) mx = fmaxf(mx, __shfl_xor(mx, off, 64));
  if (lane == 0) red[w] = mx;
  __syncthreads();
  mx = fmaxf(fmaxf(red[0], red[1]), fmaxf(red[2], red[3]));
  __syncthreads();

  float sum = 0.f;
#pragma unroll
  for (int i = 0; i < 8; i++) {
    vals[i] = __expf(vals[i] - mx);
    if (tid + i * 256 < E) sum += vals[i];
  }
#pragma unroll
  for (int off = 32; off; off >>= 1) sum += __shfl_xor(sum, off, 64);
  if (lane == 0) red[w] = sum;
  __syncthreads();
  sum = red[0] + red[1] + red[2] + red[3];

  const float scaleout = ew[h] / sum;
#pragma unroll
  for (int i = 0; i < 8; i++) {
    int j = tid + i * 256;
    if (j < E) s[j] = vals[i] * scaleout;
  }
}

// ---------------- weight rows (attn * v) + write fp32 wrow + split A panels ----------------
__global__ __launch_bounds__(256) void weight_split(
    const float* __restrict__ vd, int ldv, const float* __restrict__ attn,
    float* __restrict__ wrow, unsigned short* __restrict__ Apan, int M, int E) {
  const int row = blockIdx.x;  // < Mpad
  const int r = row & 255, mt = row >> 8;
  const int c0 = threadIdx.x * 4;
  const int kt = c0 >> 5, c = c0 & 31;
  const int q = (c >> 3) ^ ((r >> 1) & 3);
  const size_t byteoff = (size_t)r * 64 + q * 16 + (c & 7) * 2;
  char* base = (char*)Apan;
  us4 hv = (us4){0, 0, 0, 0}, lv = (us4){0, 0, 0, 0};
  if (row < M) {
    const int b = row / E, e = row - b * E;
    const float a = attn[(size_t)(b * NH + (c0 >> 6)) * E + e];
    float4 v = *(const float4*)(vd + (size_t)row * ldv + c0);
    v.x *= a; v.y *= a; v.z *= a; v.w *= a;
    *(float4*)(wrow + (size_t)row * DIMK + c0) = v;
    float vv[4] = {v.x, v.y, v.z, v.w};
#pragma unroll
    for (int i = 0; i < 4; i++) {
      unsigned short hb = f32_to_bf16_rne(vv[i]);
      hv[i] = hb;
      lv[i] = f32_to_bf16_rne(vv[i] - bf16_bits_to_f32(hb));
    }
  }
  *(us4*)(base + (((size_t)(mt * 64 + kt)) << 14) + byteoff) = hv;
  *(us4*)(base + (((size_t)(mt * 64 + 32 + kt)) << 14) + byteoff) = lv;
}

// ---------------- fold duplicate-src edges into primary rows (fp32 wrow) ----------------
__global__ __launch_bounds__(256) void dup_add(const int* __restrict__ f,
                                               float* __restrict__ wrow, int E) {
  const int e = blockIdx.x;
  const int fe = f[e];
  if (fe == e) return;
  const int d = threadIdx.x * 4;
#pragma unroll
  for (int b = 0; b < BB; b++) {
    const float4 v = *(const float4*)(wrow + (size_t)(b * E + e) * DIMK + d);
    float* dst = wrow + (size_t)(b * E + fe) * DIMK + d;
    atomicAdd(dst + 0, v.x);
    atomicAdd(dst + 1, v.y);
    atomicAdd(dst + 2, v.z);
    atomicAdd(dst + 3, v.w);
  }
}

// ---------------- re-split panels for primary rows that received duplicates ----------------
__global__ __launch_bounds__(256) void dup_fix(const int* __restrict__ fidx,
                                               const int* __restrict__ mark,
                                               const float* __restrict__ wrow,
                                               unsigned short* __restrict__ Apan, int E) {
  const int e = blockIdx.x;
  if (fidx[e] != e || !mark[e]) return;
  const int c0 = threadIdx.x * 4;
  const int kt = c0 >> 5, c = c0 & 31;
  char* base = (char*)Apan;
  for (int b = 0; b < BB; b++) {
    const int row = b * E + e;
    const int r = row & 255, mt = row >> 8;
    const int q = (c >> 3) ^ ((r >> 1) & 3);
    const size_t byteoff = (size_t)r * 64 + q * 16 + (c & 7) * 2;
    float4 v = *(const float4*)(wrow + (size_t)row * DIMK + c0);
    float vv[4] = {v.x, v.y, v.z, v.w};
    us4 hv, lv;
#pragma unroll
    for (int i = 0; i < 4; i++) {
      unsigned short hb = f32_to_bf16_rne(vv[i]);
      hv[i] = hb;
      lv[i] = f32_to_bf16_rne(vv[i] - bf16_bits_to_f32(hb));
    }
    *(us4*)(base + (((size_t)(mt * 64 + kt)) << 14) + byteoff) = hv;
    *(us4*)(base + (((size_t)(mt * 64 + 32 + kt)) << 14) + byteoff) = lv;
  }
}

extern "C" void kernel_launch(void* const* d_in, const int* in_sizes, int n_in,
                              void* d_out, int out_size, void* d_ws, size_t ws_size,
                              hipStream_t stream) {
  const float* x = (const float*)d_in[0];
  const int* src = (const int*)d_in[1];
  const int* dst = (const int*)d_in[2];
  const float* Wq = (const float*)d_in[3];
  const float* bq = (const float*)d_in[4];
  const float* Wk = (const float*)d_in[5];
  const float* bk = (const float*)d_in[6];
  const float* Wv = (const float*)d_in[7];
  const float* bv = (const float*)d_in[8];
  const float* Wo = (const float*)d_in[9];
  const float* bo = (const float*)d_in[10];
  const float* ew = (const float*)d_in[11];
  const float* W1 = (const float*)d_in[12];
  const float* b1 = (const float*)d_in[13];
  const float* W2 = (const float*)d_in[14];
  const float* b2 = (const float*)d_in[15];
  float* out = (float*)d_out;

  const int E = in_sizes[1];
  const int M = BB * E;
  const int gx = (M + 255) / 256;  // m-tiles (BM=256)
  const int Mpad = gx * 256;

  char* w = (char*)d_ws;
  float* qs = (float*)w; w += (size_t)M * DIMK * 4;   // aliased by wrow later
  float* kv = (float*)w; w += (size_t)M * 2048 * 4;
  float* sc = (float*)w; w += (size_t)BB * NH * E * 4;
  int* fidx = (int*)w; w += (((size_t)E * 4) + 255) & ~(size_t)255;
  int* mark = (int*)w; w += (((size_t)E * 4) + 255) & ~(size_t)255;
  unsigned short* W1Th = (unsigned short*)w; w += 64 * 128 * 2;
  unsigned short* W1Tl = (unsigned short*)w; w += 64 * 128 * 2;
  unsigned short* Bq = (unsigned short*)w; w += (size_t)8 * 64 * 8192;
  unsigned short* Bkv = (unsigned short*)w; w += (size_t)16 * 64 * 8192;
  unsigned short* Bo = (unsigned short*)w; w += (size_t)8 * 64 * 8192;
  unsigned short* Apan = (unsigned short*)w; w += (size_t)gx * 64 * 16384;

  float* wrow = qs;  // qs dead after edge MLP

  // 1) fill output with bo
  const int total4 = BB * SS * (DIMK / 4);
  fill_out_kernel<<<2048, 256, 0, stream>>>((const float4*)bo, (float4*)out, total4);

  // 2) weight prep (one launch) + W1 split
  prep_w4<<<dim3(16, 16, 4), 256, 0, stream>>>(Wq, Wk, Wv, Wo, Bq, Bkv, Bo);
  prep_w1<<<1, 256, 0, stream>>>(W1, W1Th, W1Tl);

  // 3) first-occurrence map + dup marks
  first_occ<<<1, 1024, 0, stream>>>(src, fidx, mark, E);

  // 4) q projection (src gather): BN=128, grid 256 (full machine)
  prep_a<<<Mpad, 256, 0, stream>>>(x, src, Apan, M, E);
  gemm8<128, 0><<<gx * 8, 512, 0, stream>>>(Apan, Bq, bq, nullptr, qs, DIMK, 8,
                                            nullptr, nullptr, M, E);

  // 5) fused k|v projection (dst gather): BN=256, grid 256
  prep_a<<<Mpad, 256, 0, stream>>>(x, dst, Apan, M, E);
  gemm8<256, 0><<<gx * 8, 512, 0, stream>>>(Apan, Bkv, bk, bv, kv, 2048, 8,
                                            nullptr, nullptr, M, E);

  // 6) edge MLP -> scores (wide grid), then softmax + edge_weight
  const int etiles = (E + 15) / 16;
  const int CH = (etiles + 3) / 4;
  edge_scores_mfma<<<BB * NH * CH, 256, 0, stream>>>(qs, kv, 2048, W1Th, W1Tl, b1, W2, b2,
                                                     sc, E, CH);
  softmax_ew<<<BB * NH, 256, 0, stream>>>(sc, ew, E);

  // 7) weighted rows + split panels; fold duplicates; re-split affected rows
  weight_split<<<Mpad, 256, 0, stream>>>(kv + 1024, 2048, sc, wrow, Apan, M, E);
  dup_add<<<E, 256, 0, stream>>>(fidx, wrow, E);
  dup_fix<<<E, 256, 0, stream>>>(fidx, mark, wrow, Apan, E);

  // 8) final GEMM: wrow @ Wo, guarded scatter-store (BN=128, grid 256)
  gemm8<128, 1><<<gx * 8, 512, 0, stream>>>(Apan, Bo, bo, nullptr, out, DIMK, 8,
                                            fidx, src, M, E);
}

// Round 12
// 333.596 us; speedup vs baseline: 1.6419x; 1.0340x over previous
//
#include <hip/hip_runtime.h>
#include <hip/hip_bf16.h>
#include <math.h>

#define DIMK 1024
#define NH 16
#define HD 64
#define BB 4
#define SS 8192
#define NKT 32  // K 1024 / BK=32

typedef __attribute__((ext_vector_type(8))) short bf16x8;
typedef __attribute__((ext_vector_type(8))) unsigned short ushort8;
typedef __attribute__((ext_vector_type(4))) unsigned short us4;
typedef __attribute__((ext_vector_type(4))) float f32x4;

#define MFMA16(a, b, c) __builtin_amdgcn_mfma_f32_16x16x32_bf16((a), (b), (c), 0, 0, 0)

__device__ __forceinline__ unsigned short f32_to_bf16_rne(float f) {
  unsigned int u = __float_as_uint(f);
  u = (u + 0x7fffu + ((u >> 16) & 1u)) >> 16;
  return (unsigned short)u;
}
__device__ __forceinline__ float bf16_bits_to_f32(unsigned short b) {
  return __uint_as_float(((unsigned int)b) << 16);
}
__device__ __forceinline__ void gload16(const void* g, void* l) {
  __builtin_amdgcn_global_load_lds((const __attribute__((address_space(1))) void*)g,
                                   (__attribute__((address_space(3))) void*)l, 16, 0, 0);
}

// ---------------- fill d_out with bo broadcast ----------------
__global__ __launch_bounds__(256) void fill_out_kernel(const float4* __restrict__ bo4,
                                                       float4* __restrict__ out, int total4) {
  for (int i = blockIdx.x * 256 + threadIdx.x; i < total4; i += gridDim.x * 256)
    out[i] = bo4[i & 255];
}

// ---------------- Wv / Wo fp32 -> tiled+swizzled bf16 hi/lo panels ----------------
__global__ __launch_bounds__(256) void prep_w2(
    const float* __restrict__ Wv, const float* __restrict__ Wo,
    unsigned short* __restrict__ Bkv, unsigned short* __restrict__ Bo) {
  const float* W = blockIdx.z ? Wo : Wv;
  unsigned short* Bpan = blockIdx.z ? Bo : Bkv;
  const int pnoff = blockIdx.z ? 0 : 8;  // Wv occupies panels 8..15 of Bkv
  __shared__ float st[64][65];
  const int bk = blockIdx.x * 64, bn = blockIdx.y * 64;
  const int t = threadIdx.x;
  const int lr = t >> 4, lc = (t & 15) * 4;
#pragma unroll
  for (int i = 0; i < 4; i++) {
    int k = lr + i * 16;
    float4 v = *(const float4*)(W + (size_t)(bk + k) * DIMK + bn + lc);
    st[k][lc] = v.x; st[k][lc + 1] = v.y; st[k][lc + 2] = v.z; st[k][lc + 3] = v.w;
  }
  __syncthreads();
  const int ktile = (bk + lc) >> 5, c = lc & 31;
#pragma unroll
  for (int i = 0; i < 4; i++) {
    const int nl = lr + i * 16;
    const int n = bn + nl;
    const int r = n & 127, pn = (n >> 7) + pnoff;
    const int q = (c >> 3) ^ ((r >> 1) & 3);
    const size_t byteoff = (size_t)r * 64 + q * 16 + (c & 7) * 2;
    us4 hv, lv;
#pragma unroll
    for (int j = 0; j < 4; j++) {
      float v = st[lc + j][nl];
      unsigned short hb = f32_to_bf16_rne(v);
      hv[j] = hb;
      lv[j] = f32_to_bf16_rne(v - bf16_bits_to_f32(hb));
    }
    char* base = (char*)Bpan;
    *(us4*)(base + (((size_t)pn * 64 + ktile) << 13) + byteoff) = hv;
    *(us4*)(base + (((size_t)pn * 64 + 32 + ktile) << 13) + byteoff) = lv;
  }
}

// ---------------- fold W1 into Wq/Wk: WQ1_h = Wq_h @ W1_top, WK1_h = Wk_h @ W1_bot ----------------
// Output written directly in B-panel (split+swizzled) format. fp32 accumulation.
__global__ __launch_bounds__(256) void prep_wfold(
    const float* __restrict__ Wq, const float* __restrict__ Wk,
    const float* __restrict__ W1,
    unsigned short* __restrict__ Bq, unsigned short* __restrict__ Bkv) {
  const int which = blockIdx.z;  // 0: q -> Bq, 1: k -> Bkv panels 0..7
  const float* W = which ? Wk : Wq;
  unsigned short* Bpan = which ? Bkv : Bq;
  const int d_off = which ? 64 : 0;
  const int cc = blockIdx.x, jc = blockIdx.y;  // c-chunk (16), head (16)
  __shared__ float Wb[64][65];   // [cl][d]
  __shared__ float W1b[64][65];  // [d][n]
  const int t = threadIdx.x;
  for (int idx = t; idx < 64 * 64; idx += 256) {
    int rrow = idx >> 6, dd = idx & 63;
    Wb[rrow][dd] = W[(size_t)(cc * 64 + rrow) * DIMK + jc * 64 + dd];
    W1b[rrow][dd] = W1[(size_t)(d_off + rrow) * 64 + dd];
  }
  __syncthreads();
  const int n = t & 63, g0 = t >> 6;
  const int pn = jc >> 1;
  const int r = (jc & 1) * 64 + n;  // panel row
  const int sw = (r >> 1) & 3;
  char* base = (char*)Bpan;
#pragma unroll
  for (int i = 0; i < 4; ++i) {
    const int cl0 = (g0 + 4 * i) * 4;
    float a0 = 0.f, a1 = 0.f, a2 = 0.f, a3 = 0.f;
    for (int d = 0; d < 64; ++d) {
      const float w1v = W1b[d][n];
      a0 = fmaf(Wb[cl0 + 0][d], w1v, a0);
      a1 = fmaf(Wb[cl0 + 1][d], w1v, a1);
      a2 = fmaf(Wb[cl0 + 2][d], w1v, a2);
      a3 = fmaf(Wb[cl0 + 3][d], w1v, a3);
    }
    float av[4] = {a0, a1, a2, a3};
    const int c = cc * 64 + cl0;
    const int kt = c >> 5, kcol = c & 31;
    const int q = (kcol >> 3) ^ sw;
    const size_t byteoff = (size_t)r * 64 + q * 16 + (kcol & 7) * 2;
    us4 hv, lv;
#pragma unroll
    for (int j = 0; j < 4; j++) {
      unsigned short hb = f32_to_bf16_rne(av[j]);
      hv[j] = hb;
      lv[j] = f32_to_bf16_rne(av[j] - bf16_bits_to_f32(hb));
    }
    *(us4*)(base + (((size_t)pn * 64 + kt) << 13) + byteoff) = hv;
    *(us4*)(base + (((size_t)pn * 64 + 32 + kt) << 13) + byteoff) = lv;
  }
}

// ---------------- folded biases: bqf = bq@W1_top ; bkf = bk@W1_bot + b1 ----------------
__global__ __launch_bounds__(256) void prep_bias(
    const float* __restrict__ bq, const float* __restrict__ bk,
    const float* __restrict__ b1, const float* __restrict__ W1,
    float* __restrict__ bqf, float* __restrict__ bkf) {
  const int j = blockIdx.x * 256 + threadIdx.x;  // grid 4
  const int h = j >> 6, n = j & 63;
  float sq = 0.f, sk = 0.f;
  for (int d = 0; d < 64; ++d) {
    sq = fmaf(bq[h * 64 + d], W1[d * 64 + n], sq);
    sk = fmaf(bk[h * 64 + d], W1[(64 + d) * 64 + n], sk);
  }
  bqf[j] = sq;
  bkf[j] = sk + b1[n];
}

// ---------------- gather rows of X -> tiled+swizzled bf16 hi/lo A panels ----------------
__global__ __launch_bounds__(256) void prep_a(const float* __restrict__ X,
                                              const int* __restrict__ gidx,
                                              unsigned short* __restrict__ Apan, int M, int E) {
  const int row = blockIdx.x;  // < Mpad
  const int r = row & 255, mt = row >> 8;
  const int c0 = threadIdx.x * 4;
  const int kt = c0 >> 5, c = c0 & 31;
  const int q = (c >> 3) ^ ((r >> 1) & 3);
  const size_t byteoff = (size_t)r * 64 + q * 16 + (c & 7) * 2;
  char* base = (char*)Apan;
  us4 hv = (us4){0, 0, 0, 0}, lv = (us4){0, 0, 0, 0};
  if (row < M) {
    const float* sr;
    if (gidx) {
      int b = row / E, e = row - b * E;
      sr = X + ((size_t)b * SS + gidx[e]) * DIMK;
    } else {
      sr = X + (size_t)row * DIMK;
    }
    float4 v = *(const float4*)(sr + c0);
    float vv[4] = {v.x, v.y, v.z, v.w};
#pragma unroll
    for (int i = 0; i < 4; i++) {
      unsigned short hb = f32_to_bf16_rne(vv[i]);
      hv[i] = hb;
      lv[i] = f32_to_bf16_rne(vv[i] - bf16_bits_to_f32(hb));
    }
  }
  *(us4*)(base + (((size_t)(mt * 64 + kt)) << 14) + byteoff) = hv;
  *(us4*)(base + (((size_t)(mt * 64 + 32 + kt)) << 14) + byteoff) = lv;
}

// ---------------- first-occurrence map, single block, LDS table ----------------
__global__ __launch_bounds__(1024) void first_occ(const int* __restrict__ src,
                                                  int* __restrict__ fidx,
                                                  int* __restrict__ mark, int E) {
  __shared__ int tbl[SS];
  for (int i = threadIdx.x; i < SS; i += 1024) tbl[i] = 0x7fffffff;
  __syncthreads();
  for (int e = threadIdx.x; e < E; e += 1024) atomicMin(&tbl[src[e]], e);
  __syncthreads();
  for (int e = threadIdx.x; e < E; e += 1024) mark[e] = 0;
  __syncthreads();
  for (int e = threadIdx.x; e < E; e += 1024) {
    int f = tbl[src[e]];
    fidx[e] = f;
    if (f != e) mark[f] = 1;
  }
}

// ---------------- fused 3-term split-bf16 GEMM (R11 schedule), BM templated ----------------
// BN=256 always. BM=256: panel per m-tile. BM=128: two m-tiles share a 256-row panel
// (rowbase = (mi&1)*128). All fragment reads upfront in pinned groups; counted lgkmcnt;
// vmcnt(0)+barrier before cluster 3 (barrier shadow covered by C3's MFMAs).
template <int BM, int MODE>
__global__ __launch_bounds__(512, 2) void gemmT(
    const unsigned short* __restrict__ Apan, const unsigned short* __restrict__ Bpan,
    const float* __restrict__ bias, const float* __restrict__ bias2,
    float* __restrict__ out, int ldc, int nty,
    const int* __restrict__ fidx, const int* __restrict__ srci, int M, int E) {
  constexpr int MF = BM / 32;  // m-frags per wave
  constexpr int NF = 4;
  constexpr int AT = BM * 32;  // ushorts per A half-tile
  __shared__ unsigned short ldsAh[2][AT];
  __shared__ unsigned short ldsAl[2][AT];
  __shared__ unsigned short ldsBh[2][8192];
  __shared__ unsigned short ldsBl[2][8192];

  const int tid = threadIdx.x, lane = tid & 63, wv = tid >> 6;
  const int wr = wv >> 2, wc = wv & 3;

  const int w = (blockIdx.x & 7) * ((int)gridDim.x >> 3) + ((int)blockIdx.x >> 3);
  const int mi = w / nty, nt_ = w - mi * nty;
  const int m0 = mi * BM, n0 = nt_ * 256;

  const int rr = lane & 15, lq = lane >> 4;
  const int swz = (rr >> 1) & 3;
  const int aoff = (wr * (BM / 2) + rr) * 32 + ((lq ^ swz) << 3);
  const int boff = (wc * 64 + rr) * 32 + ((lq ^ swz) << 3);

  const int pt = (BM == 256) ? mi : (mi >> 1);
  const int rowbase = (BM == 256) ? 0 : (mi & 1) * 128;
  const char* Apb = (const char*)Apan + (((size_t)pt * 64) << 14) + (size_t)rowbase * 64;
  const char* Bpb = (const char*)Bpan;
  const int stoff = wv * 1024 + lane * 16;

  f32x4 acc[MF][NF];
#pragma unroll
  for (int i = 0; i < MF; i++)
#pragma unroll
    for (int j = 0; j < NF; j++) acc[i][j] = (f32x4){0.f, 0.f, 0.f, 0.f};

  auto stage = [&](int kt, int buf) {
    const char* sAh = Apb + ((size_t)kt << 14) + stoff;
    const char* sAl = Apb + ((size_t)(32 + kt) << 14) + stoff;
    gload16(sAh, &ldsAh[buf][wv * 512]);
    gload16(sAl, &ldsAl[buf][wv * 512]);
    if (BM == 256) {
      gload16(sAh + 8192, &ldsAh[buf][wv * 512 + 4096]);
      gload16(sAl + 8192, &ldsAl[buf][wv * 512 + 4096]);
    }
    const char* sB0h = Bpb + (((size_t)(2 * nt_) * 64 + kt) << 13) + stoff;
    const char* sB1h = Bpb + (((size_t)(2 * nt_ + 1) * 64 + kt) << 13) + stoff;
    const char* sB0l = Bpb + (((size_t)(2 * nt_) * 64 + 32 + kt) << 13) + stoff;
    const char* sB1l = Bpb + (((size_t)(2 * nt_ + 1) * 64 + 32 + kt) << 13) + stoff;
    gload16(sB0h, &ldsBh[buf][wv * 512]);
    gload16(sB1h, &ldsBh[buf][wv * 512 + 4096]);
    gload16(sB0l, &ldsBl[buf][wv * 512]);
    gload16(sB1l, &ldsBl[buf][wv * 512 + 4096]);
  };

  stage(0, 0);
  asm volatile("s_waitcnt vmcnt(0)" ::: "memory");
  __builtin_amdgcn_sched_barrier(0);
  __builtin_amdgcn_s_barrier();

  for (int kt = 0; kt < NKT; ++kt) {
    const int buf = kt & 1;
    const unsigned short* Ah = ldsAh[buf];
    const unsigned short* Al = ldsAl[buf];
    const unsigned short* Bh = ldsBh[buf];
    const unsigned short* Bl = ldsBl[buf];

    bf16x8 fbh[NF], fah[MF], fal[MF], fbl[NF];
#pragma unroll
    for (int nf = 0; nf < NF; ++nf) fbh[nf] = *(const bf16x8*)(Bh + boff + nf * 512);
#pragma unroll
    for (int mf = 0; mf < MF; ++mf) fah[mf] = *(const bf16x8*)(Ah + aoff + mf * 512);
    __builtin_amdgcn_sched_barrier(0);
#pragma unroll
    for (int mf = 0; mf < MF; ++mf) fal[mf] = *(const bf16x8*)(Al + aoff + mf * 512);
    __builtin_amdgcn_sched_barrier(0);
#pragma unroll
    for (int nf = 0; nf < NF; ++nf) fbl[nf] = *(const bf16x8*)(Bl + boff + nf * 512);
    __builtin_amdgcn_sched_barrier(0);

    if (kt + 1 < NKT) stage(kt + 1, buf ^ 1);

    // cluster 1: ah * bh (outstanding allowed: fal(MF)+fbl(NF))
    asm volatile("s_waitcnt lgkmcnt(%0)" ::"i"(MF + NF) : "memory");
    __builtin_amdgcn_sched_barrier(0);
    __builtin_amdgcn_s_setprio(1);
#pragma unroll
    for (int mf = 0; mf < MF; ++mf)
#pragma unroll
      for (int nf = 0; nf < NF; ++nf) acc[mf][nf] = MFMA16(fah[mf], fbh[nf], acc[mf][nf]);
    __builtin_amdgcn_s_setprio(0);

    // cluster 2: al * bh (outstanding allowed: fbl(NF))
    asm volatile("s_waitcnt lgkmcnt(%0)" ::"i"(NF) : "memory");
    __builtin_amdgcn_sched_barrier(0);
    __builtin_amdgcn_s_setprio(1);
#pragma unroll
    for (int mf = 0; mf < MF; ++mf)
#pragma unroll
      for (int nf = 0; nf < NF; ++nf) acc[mf][nf] = MFMA16(fal[mf], fbh[nf], acc[mf][nf]);
    __builtin_amdgcn_s_setprio(0);

    asm volatile("s_waitcnt lgkmcnt(0)" ::: "memory");
    if (kt + 1 < NKT) {
      asm volatile("s_waitcnt vmcnt(0)" ::: "memory");
      __builtin_amdgcn_sched_barrier(0);
      __builtin_amdgcn_s_barrier();
    } else {
      __builtin_amdgcn_sched_barrier(0);
    }

    // cluster 3: ah * bl
    __builtin_amdgcn_s_setprio(1);
#pragma unroll
    for (int mf = 0; mf < MF; ++mf)
#pragma unroll
      for (int nf = 0; nf < NF; ++nf) acc[mf][nf] = MFMA16(fah[mf], fbl[nf], acc[mf][nf]);
    __builtin_amdgcn_s_setprio(0);
  }

  const int cq = lane >> 4, cr = lane & 15;
#pragma unroll
  for (int nf = 0; nf < NF; ++nf) {
    const int col = n0 + wc * 64 + nf * 16 + cr;
    const float bv = (MODE == 0 && bias2 != nullptr && col >= DIMK) ? bias2[col - DIMK]
                                                                    : bias[col & (DIMK - 1)];
#pragma unroll
    for (int mf = 0; mf < MF; ++mf) {
#pragma unroll
      for (int r = 0; r < 4; ++r) {
        const int mrow = m0 + wr * (BM / 2) + mf * 16 + cq * 4 + r;
        if (mrow >= M) continue;
        if (MODE == 0) {
          out[(size_t)mrow * ldc + col] = acc[mf][nf][r] + bv;
        } else {
          int b = mrow / E, e = mrow - b * E;
          if (fidx[e] == e) {
            int orow = b * SS + srci[e];
            out[(size_t)orow * ldc + col] = acc[mf][nf][r] + bv;
          }
        }
      }
    }
  }
}

// ---------------- edge scores from folded pre-activations: gelu + W2-dot ----------------
// h_pre[b,e,h*64+d] = hq[(b*E+e)*1024 + h*64+d] + hk[(b*E+e)*2048 + h*64+d]
__global__ __launch_bounds__(256) void edge_scores_f(
    const float* __restrict__ hq, const float* __restrict__ hk,
    const float* __restrict__ W2, const float* __restrict__ b2,
    float* __restrict__ scores, int E, int CH) {
  const int tid = threadIdx.x, lane = tid & 63, w = tid >> 6;
  const int bh = blockIdx.x / CH, ch = blockIdx.x - bh * CH;
  const int b = bh >> 4, h = bh & 15;
  const float w2 = W2[lane];
  const float b2v = b2[0];
#pragma unroll
  for (int i = 0; i < 8; ++i) {
    const int e = ch * 32 + w * 8 + i;
    if (e >= E) break;
    const size_t row = (size_t)(b * E + e);
    float hv = hq[row * 1024 + h * 64 + lane] + hk[row * 2048 + h * 64 + lane];
    hv = 0.5f * hv * (1.f + erff(hv * 0.70710678118654752f));
    float p = hv * w2;
#pragma unroll
    for (int off = 32; off; off >>= 1) p += __shfl_xor(p, off, 64);
    if (lane == 0) scores[(size_t)(b * NH + h) * E + e] = (p + b2v) * 0.125f;
  }
}

// ---------------- softmax over E per (b,h), then *= edge_weight[h] ----------------
__global__ __launch_bounds__(256) void softmax_ew(float* __restrict__ scores,
                                                  const float* __restrict__ ew, int E) {
  const int row = blockIdx.x;
  const int h = row & (NH - 1);
  float* s = scores + (size_t)row * E;
  const int tid = threadIdx.x, lane = tid & 63, w = tid >> 6;
  __shared__ float red[4];

  float vals[8];
  float mx = -1e30f;
#pragma unroll
  for (int i = 0; i < 8; i++) {
    int j = tid + i * 256;
    vals[i] = (j < E) ? s[j] : -1e30f;
    mx = fmaxf(mx, vals[i]);
  }
#pragma unroll
  for (int off = 32; off; off >>= 1) mx = fmaxf(mx, __shfl_xor(mx, off, 64));
  if (lane == 0) red[w] = mx;
  __syncthreads();
  mx = fmaxf(fmaxf(red[0], red[1]), fmaxf(red[2], red[3]));
  __syncthreads();

  float sum = 0.f;
#pragma unroll
  for (int i = 0; i < 8; i++) {
    vals[i] = __expf(vals[i] - mx);
    if (tid + i * 256 < E) sum += vals[i];
  }
#pragma unroll
  for (int off = 32; off; off >>= 1) sum += __shfl_xor(sum, off, 64);
  if (lane == 0) red[w] = sum;
  __syncthreads();
  sum = red[0] + red[1] + red[2] + red[3];

  const float scaleout = ew[h] / sum;
#pragma unroll
  for (int i = 0; i < 8; i++) {
    int j = tid + i * 256;
    if (j < E) s[j] = vals[i] * scaleout;
  }
}

// ---------------- weight rows (attn * v) + write fp32 wrow + split A panels ----------------
__global__ __launch_bounds__(256) void weight_split(
    const float* __restrict__ vd, int ldv, const float* __restrict__ attn,
    float* __restrict__ wrow, unsigned short* __restrict__ Apan, int M, int E) {
  const int row = blockIdx.x;  // < Mpad
  const int r = row & 255, mt = row >> 8;
  const int c0 = threadIdx.x * 4;
  const int kt = c0 >> 5, c = c0 & 31;
  const int q = (c >> 3) ^ ((r >> 1) & 3);
  const size_t byteoff = (size_t)r * 64 + q * 16 + (c & 7) * 2;
  char* base = (char*)Apan;
  us4 hv = (us4){0, 0, 0, 0}, lv = (us4){0, 0, 0, 0};
  if (row < M) {
    const int b = row / E, e = row - b * E;
    const float a = attn[(size_t)(b * NH + (c0 >> 6)) * E + e];
    float4 v = *(const float4*)(vd + (size_t)row * ldv + c0);
    v.x *= a; v.y *= a; v.z *= a; v.w *= a;
    *(float4*)(wrow + (size_t)row * DIMK + c0) = v;
    float vv[4] = {v.x, v.y, v.z, v.w};
#pragma unroll
    for (int i = 0; i < 4; i++) {
      unsigned short hb = f32_to_bf16_rne(vv[i]);
      hv[i] = hb;
      lv[i] = f32_to_bf16_rne(vv[i] - bf16_bits_to_f32(hb));
    }
  }
  *(us4*)(base + (((size_t)(mt * 64 + kt)) << 14) + byteoff) = hv;
  *(us4*)(base + (((size_t)(mt * 64 + 32 + kt)) << 14) + byteoff) = lv;
}

// ---------------- fold duplicate-src edges into primary rows (fp32 wrow) ----------------
__global__ __launch_bounds__(256) void dup_add(const int* __restrict__ f,
                                               float* __restrict__ wrow, int E) {
  const int e = blockIdx.x;
  const int fe = f[e];
  if (fe == e) return;
  const int d = threadIdx.x * 4;
#pragma unroll
  for (int b = 0; b < BB; b++) {
    const float4 v = *(const float4*)(wrow + (size_t)(b * E + e) * DIMK + d);
    float* dst = wrow + (size_t)(b * E + fe) * DIMK + d;
    atomicAdd(dst + 0, v.x);
    atomicAdd(dst + 1, v.y);
    atomicAdd(dst + 2, v.z);
    atomicAdd(dst + 3, v.w);
  }
}

// ---------------- re-split panels for primary rows that received duplicates ----------------
__global__ __launch_bounds__(256) void dup_fix(const int* __restrict__ fidx,
                                               const int* __restrict__ mark,
                                               const float* __restrict__ wrow,
                                               unsigned short* __restrict__ Apan, int E) {
  const int e = blockIdx.x;
  if (fidx[e] != e || !mark[e]) return;
  const int c0 = threadIdx.x * 4;
  const int kt = c0 >> 5, c = c0 & 31;
  char* base = (char*)Apan;
  for (int b = 0; b < BB; b++) {
    const int row = b * E + e;
    const int r = row & 255, mt = row >> 8;
    const int q = (c >> 3) ^ ((r >> 1) & 3);
    const size_t byteoff = (size_t)r * 64 + q * 16 + (c & 7) * 2;
    float4 v = *(const float4*)(wrow + (size_t)row * DIMK + c0);
    float vv[4] = {v.x, v.y, v.z, v.w};
    us4 hv, lv;
#pragma unroll
    for (int i = 0; i < 4; i++) {
      unsigned short hb = f32_to_bf16_rne(vv[i]);
      hv[i] = hb;
      lv[i] = f32_to_bf16_rne(vv[i] - bf16_bits_to_f32(hb));
    }
    *(us4*)(base + (((size_t)(mt * 64 + kt)) << 14) + byteoff) = hv;
    *(us4*)(base + (((size_t)(mt * 64 + 32 + kt)) << 14) + byteoff) = lv;
  }
}

extern "C" void kernel_launch(void* const* d_in, const int* in_sizes, int n_in,
                              void* d_out, int out_size, void* d_ws, size_t ws_size,
                              hipStream_t stream) {
  const float* x = (const float*)d_in[0];
  const int* src = (const int*)d_in[1];
  const int* dst = (const int*)d_in[2];
  const float* Wq = (const float*)d_in[3];
  const float* bq = (const float*)d_in[4];
  const float* Wk = (const float*)d_in[5];
  const float* bk = (const float*)d_in[6];
  const float* Wv = (const float*)d_in[7];
  const float* bv = (const float*)d_in[8];
  const float* Wo = (const float*)d_in[9];
  const float* bo = (const float*)d_in[10];
  const float* ew = (const float*)d_in[11];
  const float* W1 = (const float*)d_in[12];
  const float* b1 = (const float*)d_in[13];
  const float* W2 = (const float*)d_in[14];
  const float* b2 = (const float*)d_in[15];
  float* out = (float*)d_out;

  const int E = in_sizes[1];
  const int M = BB * E;
  const int gx = (M + 255) / 256;        // 256-row panel count
  const int Mpad = gx * 256;
  const int mi128 = gx * 2;              // BM=128 m-tiles (panel-sharing)

  char* w = (char*)d_ws;
  float* qs = (float*)w; w += (size_t)M * DIMK * 4;   // h_pre q-part; aliased by wrow later
  float* kv = (float*)w; w += (size_t)M * 2048 * 4;   // [h_pre k-part | v]
  float* sc = (float*)w; w += (size_t)BB * NH * E * 4;
  int* fidx = (int*)w; w += (((size_t)E * 4) + 255) & ~(size_t)255;
  int* mark = (int*)w; w += (((size_t)E * 4) + 255) & ~(size_t)255;
  float* bqf = (float*)w; w += 1024 * 4;
  float* bkf = (float*)w; w += 1024 * 4;
  unsigned short* Bq = (unsigned short*)w; w += (size_t)8 * 64 * 8192;
  unsigned short* Bkv = (unsigned short*)w; w += (size_t)16 * 64 * 8192;
  unsigned short* Bo = (unsigned short*)w; w += (size_t)8 * 64 * 8192;
  unsigned short* Apan = (unsigned short*)w; w += (size_t)gx * 64 * 16384;

  float* wrow = qs;  // qs dead after edge scores

  // 1) fill output with bo
  const int total4 = BB * SS * (DIMK / 4);
  fill_out_kernel<<<2048, 256, 0, stream>>>((const float4*)bo, (float4*)out, total4);

  // 2) weight prep: Wv/Wo panels; W1-folded WQ1/WK1 panels; folded biases
  prep_w2<<<dim3(16, 16, 2), 256, 0, stream>>>(Wv, Wo, Bkv, Bo);
  prep_wfold<<<dim3(16, 16, 2), 256, 0, stream>>>(Wq, Wk, W1, Bq, Bkv);
  prep_bias<<<4, 256, 0, stream>>>(bq, bk, b1, W1, bqf, bkf);

  // 3) first-occurrence map + dup marks
  first_occ<<<1, 1024, 0, stream>>>(src, fidx, mark, E);

  // 4) q-part of h_pre: x_src @ WQ1 + bqf  (BM=128, grid mi128*4 = 256)
  prep_a<<<Mpad, 256, 0, stream>>>(x, src, Apan, M, E);
  gemmT<128, 0><<<mi128 * 4, 512, 0, stream>>>(Apan, Bq, bqf, nullptr, qs, DIMK, 4,
                                               nullptr, nullptr, M, E);

  // 5) [k-part of h_pre | v]: x_dst @ [WK1 | Wv] + [bkf | bv]  (BM=256, grid 256)
  prep_a<<<Mpad, 256, 0, stream>>>(x, dst, Apan, M, E);
  gemmT<256, 0><<<gx * 8, 512, 0, stream>>>(Apan, Bkv, bkf, bv, kv, 2048, 8,
                                            nullptr, nullptr, M, E);

  // 6) edge scores (gelu + W2 dot), then softmax + edge_weight
  const int CH = (E + 31) / 32;
  edge_scores_f<<<BB * NH * CH, 256, 0, stream>>>(qs, kv, W2, b2, sc, E, CH);
  softmax_ew<<<BB * NH, 256, 0, stream>>>(sc, ew, E);

  // 7) weighted rows + split panels; fold duplicates; re-split affected rows
  weight_split<<<Mpad, 256, 0, stream>>>(kv + 1024, 2048, sc, wrow, Apan, M, E);
  dup_add<<<E, 256, 0, stream>>>(fidx, wrow, E);
  dup_fix<<<E, 256, 0, stream>>>(fidx, mark, wrow, Apan, E);

  // 8) final GEMM: wrow @ Wo, guarded scatter-store (BM=128, grid 256)
  gemmT<128, 1><<<mi128 * 4, 512, 0, stream>>>(Apan, Bo, bo, nullptr, out, DIMK, 4,
                                               fidx, src, M, E);
}